// Round 1
// baseline (1112.466 us; speedup 1.0000x reference)
//
#include <hip/hip_runtime.h>
#include <math.h>

// Problem constants
// B=2, L=1024, C=64, R=32, RV=32, DQK=64, H=8, NSINK=4
// x: (2,1024,64,32) fp32; out same.

// ---------------------------------------------------------------------------
// Generic tiled fp32 GEMM: C[M,N] = A[M,K] @ B[K,N] (+ bias[N]), row-major,
// batched via z strides. 64x64 tile, 256 threads, 4x4 per thread, BK=16.
// ---------------------------------------------------------------------------
__global__ __launch_bounds__(256) void gemm_bias_kernel(
    const float* __restrict__ A, int lda, long sA,
    const float* __restrict__ Bm, int ldb, long sB,
    const float* __restrict__ bias,
    float* __restrict__ Cm, int ldc, long sC,
    int M, int N, int K)
{
    A  += (long)blockIdx.z * sA;
    Bm += (long)blockIdx.z * sB;
    Cm += (long)blockIdx.z * sC;

    __shared__ float As[16][68];   // padded to 68 (multiple of 4 -> float4 ok)
    __shared__ float Bs[16][68];

    const int tid = threadIdx.x;
    const int tn = tid & 15;       // 16 cols of threads
    const int tm = tid >> 4;       // 16 rows of threads
    const int row0 = blockIdx.y * 64;
    const int col0 = blockIdx.x * 64;

    float acc[4][4] = {{0.f}};

    for (int k0 = 0; k0 < K; k0 += 16) {
        // load A tile: 64 rows x 16 k
        for (int i = tid; i < 64 * 16; i += 256) {
            int mm = i >> 4, kk = i & 15;
            int rr = row0 + mm;
            As[kk][mm] = (rr < M) ? A[(long)rr * lda + (k0 + kk)] : 0.f;
        }
        // load B tile: 16 k x 64 cols
        for (int i = tid; i < 16 * 64; i += 256) {
            int kk = i >> 6, nn = i & 63;
            int cc = col0 + nn;
            Bs[kk][nn] = (cc < N) ? Bm[(long)(k0 + kk) * ldb + cc] : 0.f;
        }
        __syncthreads();
        #pragma unroll
        for (int kk = 0; kk < 16; ++kk) {
            float4 av = *reinterpret_cast<const float4*>(&As[kk][tm * 4]);
            float4 bv = *reinterpret_cast<const float4*>(&Bs[kk][tn * 4]);
            float a[4] = {av.x, av.y, av.z, av.w};
            float b[4] = {bv.x, bv.y, bv.z, bv.w};
            #pragma unroll
            for (int i = 0; i < 4; ++i)
                #pragma unroll
                for (int j = 0; j < 4; ++j)
                    acc[i][j] += a[i] * b[j];
        }
        __syncthreads();
    }

    #pragma unroll
    for (int i = 0; i < 4; ++i) {
        int rr = row0 + tm * 4 + i;
        if (rr >= M) continue;
        #pragma unroll
        for (int j = 0; j < 4; ++j) {
            int cc = col0 + tn * 4 + j;
            if (cc < N) {
                float vv = acc[i][j];
                if (bias) vv += bias[cc];
                Cm[(long)rr * ldc + cc] = vv;
            }
        }
    }
}

// ---------------------------------------------------------------------------
// Per-channel value projection: v[bl,c,o] = sum_r x[bl,c,r]*Wv[c,r,o] + bv[c,o]
// grid (C=64, BL/64=32), block 256 = 8 rows x 32 o
// ---------------------------------------------------------------------------
__global__ __launch_bounds__(256) void vproj_kernel(
    const float* __restrict__ x, const float* __restrict__ Wv,
    const float* __restrict__ bv, float* __restrict__ v)
{
    const int c = blockIdx.x;
    const int bl0 = blockIdx.y * 64;
    const int tid = threadIdx.x;
    __shared__ float Wc[32][33];
    for (int i = tid; i < 1024; i += 256) {
        int r = i >> 5, o = i & 31;
        Wc[r][o] = Wv[(c * 32 + r) * 32 + o];
    }
    __syncthreads();
    const int o = tid & 31;
    const int rgrp = tid >> 5;
    const float bvo = bv[c * 32 + o];
    for (int it = 0; it < 8; ++it) {
        int row = bl0 + it * 8 + rgrp;
        const float* xp = &x[(long)row * 2048 + c * 32];
        float acc = bvo;
        #pragma unroll
        for (int r = 0; r < 32; ++r) acc += xp[r] * Wc[r][o];
        v[(long)row * 2048 + c * 32 + o] = acc;
    }
}

// ---------------------------------------------------------------------------
// Attention: per (b,l) block computes logits over s for all 8 heads,
// fp32 softmax per head, head-averaged P row: P[b,l,s] = (1/8) sum_h attn.
// P layout: (B, L+1, S) with row L reserved for the sink weights.
// ---------------------------------------------------------------------------
__global__ __launch_bounds__(256) void attn_kernel(
    const float* __restrict__ q, const float* __restrict__ k,
    float* __restrict__ P)
{
    const int bl = blockIdx.x;               // 0..2047
    const int b = bl >> 10;
    const int l = bl & 1023;
    const int tid = threadIdx.x;

    __shared__ float qT[64][8];              // q transposed [d][h]
    __shared__ float lg[8][1024];
    __shared__ float mx[8], invden[8];

    for (int i = tid; i < 512; i += 256) {
        int h = i >> 6, d = i & 63;
        qT[d][h] = q[(long)bl * 512 + i];
    }
    __syncthreads();

    const float scale = 0.125f;              // 1/sqrt(64)
    for (int s = tid; s < 1024; s += 256) {
        const float4* kp = reinterpret_cast<const float4*>(&k[((long)(b << 10) + s) * 64]);
        float acc[8] = {0.f, 0.f, 0.f, 0.f, 0.f, 0.f, 0.f, 0.f};
        #pragma unroll
        for (int d4 = 0; d4 < 16; ++d4) {
            float4 kv = kp[d4];
            float kd[4] = {kv.x, kv.y, kv.z, kv.w};
            #pragma unroll
            for (int j = 0; j < 4; ++j) {
                int d = d4 * 4 + j;
                float4 qa = *reinterpret_cast<const float4*>(&qT[d][0]);
                float4 qb = *reinterpret_cast<const float4*>(&qT[d][4]);
                acc[0] += qa.x * kd[j]; acc[1] += qa.y * kd[j];
                acc[2] += qa.z * kd[j]; acc[3] += qa.w * kd[j];
                acc[4] += qb.x * kd[j]; acc[5] += qb.y * kd[j];
                acc[6] += qb.z * kd[j]; acc[7] += qb.w * kd[j];
            }
        }
        #pragma unroll
        for (int h = 0; h < 8; ++h) lg[h][s] = acc[h] * scale;
    }
    __syncthreads();

    // per-head max (32 threads per head)
    {
        int h = tid >> 5, j = tid & 31;
        float pm = -1e30f;
        for (int s = j; s < 1024; s += 32) pm = fmaxf(pm, lg[h][s]);
        #pragma unroll
        for (int off = 16; off > 0; off >>= 1) pm = fmaxf(pm, __shfl_down(pm, off, 32));
        if (j == 0) mx[h] = pm;
    }
    __syncthreads();
    // exp + per-head sum
    {
        int h = tid >> 5, j = tid & 31;
        float m = mx[h];
        float ps = 0.f;
        for (int s = j; s < 1024; s += 32) {
            float e = __expf(lg[h][s] - m);
            lg[h][s] = e;
            ps += e;
        }
        #pragma unroll
        for (int off = 16; off > 0; off >>= 1) ps += __shfl_down(ps, off, 32);
        if (j == 0) invden[h] = 1.f / ps;
    }
    __syncthreads();

    float w[8];
    #pragma unroll
    for (int h = 0; h < 8; ++h) w[h] = invden[h] * 0.125f;  // 1/H
    for (int s = tid; s < 1024; s += 256) {
        float p = 0.f;
        #pragma unroll
        for (int h = 0; h < 8; ++h) p += lg[h][s] * w[h];
        P[((long)b * 1025 + l) * 1024 + s] = p;
    }
}

// ---------------------------------------------------------------------------
// Sink branch: one block per (b, h, si). Softmax over l of sink_q . k, then
// atomicAdd (1/32)*attn into P row 1024 of batch b (pre-zeroed).
// ---------------------------------------------------------------------------
__global__ __launch_bounds__(256) void sink_kernel(
    const float* __restrict__ sink_q, const float* __restrict__ k,
    float* __restrict__ P)
{
    const int z = blockIdx.x;                // 0..63
    const int b = z >> 5;
    const int idx = z & 31;                  // h*4+si, matches sink_q row order
    const int tid = threadIdx.x;

    __shared__ float sq[64];
    __shared__ float lgl[1024];
    __shared__ float red[4];
    __shared__ float mxs, invs;

    if (tid < 64) sq[tid] = sink_q[idx * 64 + tid];
    __syncthreads();

    float lmax = -1e30f;
    for (int l = tid; l < 1024; l += 256) {
        const float4* kp = reinterpret_cast<const float4*>(&k[((long)(b << 10) + l) * 64]);
        const float4* sp = reinterpret_cast<const float4*>(sq);
        float acc = 0.f;
        #pragma unroll
        for (int d4 = 0; d4 < 16; ++d4) {
            float4 kv = kp[d4];
            float4 sv = sp[d4];
            acc += kv.x * sv.x + kv.y * sv.y + kv.z * sv.z + kv.w * sv.w;
        }
        acc *= 0.125f;
        lgl[l] = acc;
        lmax = fmaxf(lmax, acc);
    }
    #pragma unroll
    for (int off = 32; off > 0; off >>= 1) lmax = fmaxf(lmax, __shfl_down(lmax, off, 64));
    if ((tid & 63) == 0) red[tid >> 6] = lmax;
    __syncthreads();
    if (tid == 0) mxs = fmaxf(fmaxf(red[0], red[1]), fmaxf(red[2], red[3]));
    __syncthreads();

    const float m = mxs;
    float psum = 0.f;
    for (int l = tid; l < 1024; l += 256) {
        float e = __expf(lgl[l] - m);
        lgl[l] = e;
        psum += e;
    }
    #pragma unroll
    for (int off = 32; off > 0; off >>= 1) psum += __shfl_down(psum, off, 64);
    if ((tid & 63) == 0) red[tid >> 6] = psum;
    __syncthreads();
    if (tid == 0) invs = 1.f / (red[0] + red[1] + red[2] + red[3]);
    __syncthreads();

    const float wgt = invs * (1.f / 32.f);   // 1/(H*NSINK)
    float* Prow = &P[((long)b * 1025 + 1024) * 1024];
    for (int l = tid; l < 1024; l += 256) {
        atomicAdd(&Prow[l], lgl[l] * wgt);
    }
}

// ---------------------------------------------------------------------------
// Output: out[bl,c,r] = x[bl,c,r] + bo[c,r]
//                       + sum_o (Y[b,l,c,o] + Y[b,1024,c,o]) * Wo[c,o,r]
// ---------------------------------------------------------------------------
__global__ __launch_bounds__(256) void out_kernel(
    const float* __restrict__ x, const float* __restrict__ Y,
    const float* __restrict__ Wo, const float* __restrict__ bo,
    float* __restrict__ out)
{
    const int c = blockIdx.x;
    const int bl0 = blockIdx.y * 64;
    const int b = bl0 >> 10;                 // chunk never straddles batches
    const int tid = threadIdx.x;

    __shared__ float Woc[32][33];
    __shared__ float ys[32];
    for (int i = tid; i < 1024; i += 256) {
        int o = i >> 5, r = i & 31;
        Woc[o][r] = Wo[(c * 32 + o) * 32 + r];
    }
    if (tid < 32) ys[tid] = Y[((long)b * 1025 + 1024) * 2048 + c * 32 + tid];
    __syncthreads();

    const int r = tid & 31;
    const int rgrp = tid >> 5;
    const float bor = bo[c * 32 + r];
    for (int it = 0; it < 8; ++it) {
        int bl = bl0 + it * 8 + rgrp;
        int l = bl & 1023;
        const float* yp = &Y[((long)b * 1025 + l) * 2048 + c * 32];
        float acc = bor;
        #pragma unroll
        for (int o = 0; o < 32; ++o) acc += (yp[o] + ys[o]) * Woc[o][r];
        long oi = (long)bl * 2048 + c * 32 + r;
        out[oi] = x[oi] + acc;
    }
}

// ---------------------------------------------------------------------------
extern "C" void kernel_launch(void* const* d_in, const int* in_sizes, int n_in,
                              void* d_out, int out_size, void* d_ws, size_t ws_size,
                              hipStream_t stream)
{
    const float* x  = (const float*)d_in[0];
    const float* Wq = (const float*)d_in[1];
    const float* bq = (const float*)d_in[2];
    const float* Wk = (const float*)d_in[3];
    const float* bk = (const float*)d_in[4];
    const float* Wv = (const float*)d_in[5];
    const float* bv = (const float*)d_in[6];
    const float* Wo = (const float*)d_in[7];
    const float* bo = (const float*)d_in[8];
    const float* sq = (const float*)d_in[9];
    float* out = (float*)d_out;

    float* ws = (float*)d_ws;
    float* q = ws;                    // 2*1024*512   = 1,048,576
    float* k = q + 1048576;           // 2*1024*64    =   131,072
    float* v = k + 131072;            // 2*1024*2048  = 4,194,304
    float* P = v + 4194304;           // 2*1025*1024  = 2,099,200
    float* Y = P + 2099200;           // 2*1025*2048  = 4,198,400
    // total ~46.7 MB of d_ws

    dim3 blk(256);

    // q projection: (2048 x 2048) @ (2048 x 512) + bq
    gemm_bias_kernel<<<dim3(8, 32, 1), blk, 0, stream>>>(
        x, 2048, 0, Wq, 512, 0, bq, q, 512, 0, 2048, 512, 2048);
    // k projection: (2048 x 2048) @ (2048 x 64) + bk
    gemm_bias_kernel<<<dim3(1, 32, 1), blk, 0, stream>>>(
        x, 2048, 0, Wk, 64, 0, bk, k, 64, 0, 2048, 64, 2048);
    // v projection
    vproj_kernel<<<dim3(64, 32), blk, 0, stream>>>(x, Wv, bv, v);
    // head-averaged attention rows
    attn_kernel<<<dim3(2048), blk, 0, stream>>>(q, k, P);
    // zero the two sink rows (P row index 1024 per batch), then accumulate
    hipMemsetAsync(P + (long)1024 * 1024, 0, 1024 * sizeof(float), stream);
    hipMemsetAsync(P + (long)2049 * 1024, 0, 1024 * sizeof(float), stream);
    sink_kernel<<<dim3(64), blk, 0, stream>>>(sq, k, P);
    // Y = P_ext @ v  : per batch (1025 x 1024) @ (1024 x 2048)
    gemm_bias_kernel<<<dim3(32, 17, 2), blk, 0, stream>>>(
        P, 1024, (long)1025 * 1024, v, 2048, (long)1024 * 2048, nullptr,
        Y, 2048, (long)1025 * 2048, 1025, 2048, 1024);
    // epilogue: out = x + (y + y_sink) @ Wo[c] + bo
    out_kernel<<<dim3(64, 32), blk, 0, stream>>>(x, Y, Wo, bo, out);
}

// Round 2
// 423.573 us; speedup vs baseline: 2.6264x; 2.6264x over previous
//
#include <hip/hip_runtime.h>
#include <hip/hip_bf16.h>
#include <math.h>

// B=2, L=1024, C=64, R=32, RV=32, DQK=64, H=8, NSINK=4
// x: (2,1024,64,32) fp32; out same. BL = 2048.

typedef __attribute__((ext_vector_type(8))) short short8;
typedef __attribute__((ext_vector_type(4))) short short4v;
typedef __attribute__((ext_vector_type(4))) float float4v;

__device__ __forceinline__ short f2b(float f) {
    __hip_bfloat16 h = __float2bfloat16(f);
    return __builtin_bit_cast(short, h);
}

// ---------------------------------------------------------------------------
// fp32 -> bf16 elementwise (x conversion). n must be multiple of 1024.
// ---------------------------------------------------------------------------
__global__ __launch_bounds__(256) void convert_x_kernel(
    const float* __restrict__ src, short* __restrict__ dst, int n4)
{
    int id = blockIdx.x * 256 + threadIdx.x;
    if (id >= n4) return;
    float4 v = reinterpret_cast<const float4*>(src)[id];
    short4v o;
    o[0] = f2b(v.x); o[1] = f2b(v.y); o[2] = f2b(v.z); o[3] = f2b(v.w);
    reinterpret_cast<short4v*>(dst)[id] = o;
}

// ---------------------------------------------------------------------------
// Build transposed bf16 weight Wt[n][k], n in [0,576): col n<512 from Wq
// (2048x512), else from Wk (2048x64). 64x64 LDS tile transpose.
// grid (9, 32): (n-tile, k-tile)
// ---------------------------------------------------------------------------
__global__ __launch_bounds__(256) void convert_w_kernel(
    const float* __restrict__ Wq, const float* __restrict__ Wk,
    short* __restrict__ Wt)
{
    const int n0 = blockIdx.x * 64;
    const int k0 = blockIdx.y * 64;
    const int tid = threadIdx.x;
    __shared__ float ts[64][65];
    // coalesced read: value(k, n)
    for (int i = tid; i < 4096; i += 256) {
        int kk = i >> 6, nn = i & 63;
        int n = n0 + nn, k = k0 + kk;
        float v = (n < 512) ? Wq[(long)k * 512 + n] : Wk[(long)k * 64 + (n - 512)];
        ts[kk][nn] = v;
    }
    __syncthreads();
    // coalesced write along k
    for (int i = tid; i < 4096; i += 256) {
        int nn = i >> 6, kk = i & 63;
        Wt[(long)(n0 + nn) * 2048 + k0 + kk] = f2b(ts[kk][nn]);
    }
}

__global__ void bias_fuse_kernel(const float* __restrict__ bq,
                                 const float* __restrict__ bk,
                                 float* __restrict__ biasqk)
{
    int t = threadIdx.x;   // block of 576
    biasqk[t] = (t < 512) ? bq[t] : bk[t - 512];
}

// ---------------------------------------------------------------------------
// bf16 MFMA GEMM: C[M,N] fp32 = A[M,K] @ Bt[N,K]^T (+bias), A either bf16
// row-major or fp32 row-major (converted during staging). 64x64 tile,
// 256 thr = 4 waves in 2x2, each wave 32x32 via 2x2 mfma_f32_16x16x32_bf16.
// ---------------------------------------------------------------------------
template <bool AF32>
__global__ __launch_bounds__(256) void mfma_gemm_kernel(
    const void* __restrict__ Aptr, int lda, long sA,
    const short* __restrict__ Bt, int ldb, long sB,
    const float* __restrict__ bias,
    float* __restrict__ Cm, int ldc, long sC,
    int M, int N, int K)
{
    const short* Ab = (const short*)Aptr;
    const float* Af = (const float*)Aptr;
    Ab += (long)blockIdx.z * sA;
    Af += (long)blockIdx.z * sA;
    const short* Bz = Bt + (long)blockIdx.z * sB;
    float* Cz = Cm + (long)blockIdx.z * sC;

    __shared__ short As[64][72];
    __shared__ short Bs[64][72];

    const int tid = threadIdx.x;
    const int wave = tid >> 6;
    const int lane = tid & 63;
    const int wm = wave >> 1, wn = wave & 1;
    const int m15 = lane & 15;
    const int quad = lane >> 4;
    const int row0 = blockIdx.y * 64;
    const int col0 = blockIdx.x * 64;

    float4v acc[2][2];
    #pragma unroll
    for (int i = 0; i < 2; ++i)
        #pragma unroll
        for (int j = 0; j < 2; ++j)
            #pragma unroll
            for (int r = 0; r < 4; ++r) acc[i][j][r] = 0.f;

    for (int k0 = 0; k0 < K; k0 += 64) {
        if (AF32) {
            // 64 rows x 64 k, 4 floats per thread -> 4 bf16
            #pragma unroll
            for (int p = 0; p < 4; ++p) {
                int i = tid + p * 256;
                int m = i >> 4, kq = i & 15;
                int rr = row0 + m;
                float4 v = {0.f, 0.f, 0.f, 0.f};
                if (rr < M) v = *reinterpret_cast<const float4*>(&Af[(long)rr * lda + k0 + kq * 4]);
                short4v o;
                o[0] = f2b(v.x); o[1] = f2b(v.y); o[2] = f2b(v.z); o[3] = f2b(v.w);
                *reinterpret_cast<short4v*>(&As[m][kq * 4]) = o;
            }
        } else {
            // 64 rows x 64 k, 8 bf16 per thread
            #pragma unroll
            for (int p = 0; p < 2; ++p) {
                int i = tid + p * 256;
                int m = i >> 3, kq = i & 7;
                int rr = row0 + m;
                short8 v = {0, 0, 0, 0, 0, 0, 0, 0};
                if (rr < M) v = *reinterpret_cast<const short8*>(&Ab[(long)rr * lda + k0 + kq * 8]);
                *reinterpret_cast<short8*>(&As[m][kq * 8]) = v;
            }
        }
        // B tile: 64 cols(n) x 64 k from Bt[n][k]
        #pragma unroll
        for (int p = 0; p < 2; ++p) {
            int i = tid + p * 256;
            int n = i >> 3, kq = i & 7;
            short8 v = *reinterpret_cast<const short8*>(&Bz[(long)(col0 + n) * ldb + k0 + kq * 8]);
            *reinterpret_cast<short8*>(&Bs[n][kq * 8]) = v;
        }
        __syncthreads();

        #pragma unroll
        for (int ks = 0; ks < 2; ++ks) {
            short8 a[2], b[2];
            #pragma unroll
            for (int t = 0; t < 2; ++t) {
                a[t] = *reinterpret_cast<const short8*>(&As[wm * 32 + t * 16 + m15][ks * 32 + quad * 8]);
                b[t] = *reinterpret_cast<const short8*>(&Bs[wn * 32 + t * 16 + m15][ks * 32 + quad * 8]);
            }
            #pragma unroll
            for (int ti = 0; ti < 2; ++ti)
                #pragma unroll
                for (int tj = 0; tj < 2; ++tj)
                    acc[ti][tj] = __builtin_amdgcn_mfma_f32_16x16x32_bf16(
                        a[ti], b[tj], acc[ti][tj], 0, 0, 0);
        }
        __syncthreads();
    }

    #pragma unroll
    for (int ti = 0; ti < 2; ++ti) {
        #pragma unroll
        for (int r = 0; r < 4; ++r) {
            int row = row0 + wm * 32 + ti * 16 + quad * 4 + r;
            if (row >= M) continue;
            #pragma unroll
            for (int tj = 0; tj < 2; ++tj) {
                int col = col0 + wn * 32 + tj * 16 + m15;
                float vv = acc[ti][tj][r];
                if (bias) vv += bias[col];
                Cz[(long)row * ldc + col] = vv;
            }
        }
    }
}

// ---------------------------------------------------------------------------
// Per-channel value projection, writes TRANSPOSED bf16: vt[b][c*32+o][l]
// grid (C=64, 32 chunks of 64 bl), block 256 = 64 s x 4 o-groups
// ---------------------------------------------------------------------------
__global__ __launch_bounds__(256) void vproj_kernel(
    const float* __restrict__ x, const float* __restrict__ Wv,
    const float* __restrict__ bv, short* __restrict__ vt)
{
    const int c = blockIdx.x;
    const int chunk = blockIdx.y;       // 0..31
    const int b = chunk >> 4;
    const int l0 = (chunk & 15) * 64;
    const int tid = threadIdx.x;
    __shared__ float Wc[32][33];
    __shared__ float xs[64][33];
    for (int i = tid; i < 1024; i += 256)
        Wc[i >> 5][i & 31] = Wv[(c * 32 + (i >> 5)) * 32 + (i & 31)];
    for (int i = tid; i < 2048; i += 256) {
        int s = i >> 5, r = i & 31;
        xs[s][r] = x[((long)(b << 10) + l0 + s) * 2048 + c * 32 + r];
    }
    __syncthreads();
    const int s = tid & 63;
    const int og = tid >> 6;
    #pragma unroll
    for (int oi = 0; oi < 8; ++oi) {
        int o = og * 8 + oi;
        float acc = bv[c * 32 + o];
        #pragma unroll
        for (int r = 0; r < 32; ++r) acc += xs[s][r] * Wc[r][o];
        vt[(long)b * (2048 * 1024) + (long)(c * 32 + o) * 1024 + l0 + s] = f2b(acc);
    }
}

// ---------------------------------------------------------------------------
// Attention: per (b,l) block, 8-head logits over s, fp32 softmax,
// head-averaged row P[b,l,s] (fp32). q,k live fused in qk (ld 576, k at +512).
// ---------------------------------------------------------------------------
__global__ __launch_bounds__(256) void attn_kernel(
    const float* __restrict__ qk, float* __restrict__ P)
{
    const int bl = blockIdx.x;
    const int b = bl >> 10;
    const int l = bl & 1023;
    const int tid = threadIdx.x;

    __shared__ float qT[64][8];
    __shared__ float lg[8][1024];
    __shared__ float mx[8], invden[8];

    for (int i = tid; i < 512; i += 256) {
        int h = i >> 6, d = i & 63;
        qT[d][h] = qk[(long)bl * 576 + i];
    }
    __syncthreads();

    const float scale = 0.125f;
    for (int s = tid; s < 1024; s += 256) {
        const float4* kp = reinterpret_cast<const float4*>(&qk[((long)(b << 10) + s) * 576 + 512]);
        float acc[8] = {0.f, 0.f, 0.f, 0.f, 0.f, 0.f, 0.f, 0.f};
        #pragma unroll
        for (int d4 = 0; d4 < 16; ++d4) {
            float4 kv = kp[d4];
            float kd[4] = {kv.x, kv.y, kv.z, kv.w};
            #pragma unroll
            for (int j = 0; j < 4; ++j) {
                int d = d4 * 4 + j;
                float4 qa = *reinterpret_cast<const float4*>(&qT[d][0]);
                float4 qb = *reinterpret_cast<const float4*>(&qT[d][4]);
                acc[0] += qa.x * kd[j]; acc[1] += qa.y * kd[j];
                acc[2] += qa.z * kd[j]; acc[3] += qa.w * kd[j];
                acc[4] += qb.x * kd[j]; acc[5] += qb.y * kd[j];
                acc[6] += qb.z * kd[j]; acc[7] += qb.w * kd[j];
            }
        }
        #pragma unroll
        for (int h = 0; h < 8; ++h) lg[h][s] = acc[h] * scale;
    }
    __syncthreads();

    {
        int h = tid >> 5, j = tid & 31;
        float pm = -1e30f;
        for (int s = j; s < 1024; s += 32) pm = fmaxf(pm, lg[h][s]);
        #pragma unroll
        for (int off = 16; off > 0; off >>= 1) pm = fmaxf(pm, __shfl_down(pm, off, 32));
        if (j == 0) mx[h] = pm;
    }
    __syncthreads();
    {
        int h = tid >> 5, j = tid & 31;
        float m = mx[h];
        float ps = 0.f;
        for (int s = j; s < 1024; s += 32) {
            float e = __expf(lg[h][s] - m);
            lg[h][s] = e;
            ps += e;
        }
        #pragma unroll
        for (int off = 16; off > 0; off >>= 1) ps += __shfl_down(ps, off, 32);
        if (j == 0) invden[h] = 1.f / ps;
    }
    __syncthreads();

    float w[8];
    #pragma unroll
    for (int h = 0; h < 8; ++h) w[h] = invden[h] * 0.125f;
    for (int s = tid; s < 1024; s += 256) {
        float p = 0.f;
        #pragma unroll
        for (int h = 0; h < 8; ++h) p += lg[h][s] * w[h];
        P[((long)b * 1025 + l) * 1024 + s] = p;
    }
}

// ---------------------------------------------------------------------------
// Sink branch -> atomicAdd into P row 1024 per batch (pre-zeroed).
// ---------------------------------------------------------------------------
__global__ __launch_bounds__(256) void sink_kernel(
    const float* __restrict__ sink_q, const float* __restrict__ qk,
    float* __restrict__ P)
{
    const int z = blockIdx.x;
    const int b = z >> 5;
    const int idx = z & 31;
    const int tid = threadIdx.x;

    __shared__ float sq[64];
    __shared__ float lgl[1024];
    __shared__ float red[4];
    __shared__ float mxs, invs;

    if (tid < 64) sq[tid] = sink_q[idx * 64 + tid];
    __syncthreads();

    float lmax = -1e30f;
    for (int l = tid; l < 1024; l += 256) {
        const float4* kp = reinterpret_cast<const float4*>(&qk[((long)(b << 10) + l) * 576 + 512]);
        const float4* sp = reinterpret_cast<const float4*>(sq);
        float acc = 0.f;
        #pragma unroll
        for (int d4 = 0; d4 < 16; ++d4) {
            float4 kv = kp[d4];
            float4 sv = sp[d4];
            acc += kv.x * sv.x + kv.y * sv.y + kv.z * sv.z + kv.w * sv.w;
        }
        acc *= 0.125f;
        lgl[l] = acc;
        lmax = fmaxf(lmax, acc);
    }
    #pragma unroll
    for (int off = 32; off > 0; off >>= 1) lmax = fmaxf(lmax, __shfl_down(lmax, off, 64));
    if ((tid & 63) == 0) red[tid >> 6] = lmax;
    __syncthreads();
    if (tid == 0) mxs = fmaxf(fmaxf(red[0], red[1]), fmaxf(red[2], red[3]));
    __syncthreads();

    const float m = mxs;
    float psum = 0.f;
    for (int l = tid; l < 1024; l += 256) {
        float e = __expf(lgl[l] - m);
        lgl[l] = e;
        psum += e;
    }
    #pragma unroll
    for (int off = 32; off > 0; off >>= 1) psum += __shfl_down(psum, off, 64);
    if ((tid & 63) == 0) red[tid >> 6] = psum;
    __syncthreads();
    if (tid == 0) invs = 1.f / (red[0] + red[1] + red[2] + red[3]);
    __syncthreads();

    const float wgt = invs * (1.f / 32.f);
    float* Prow = &P[((long)b * 1025 + 1024) * 1024];
    for (int l = tid; l < 1024; l += 256) {
        atomicAdd(&Prow[l], lgl[l] * wgt);
    }
}

// ---------------------------------------------------------------------------
// out[bl,c,r] = x + bo + sum_o (Y[b,l,c,o] + Y[b,1024,c,o]) * Wo[c,o,r]
// ---------------------------------------------------------------------------
__global__ __launch_bounds__(256) void out_kernel(
    const float* __restrict__ x, const float* __restrict__ Y,
    const float* __restrict__ Wo, const float* __restrict__ bo,
    float* __restrict__ out)
{
    const int c = blockIdx.x;
    const int bl0 = blockIdx.y * 64;
    const int b = bl0 >> 10;
    const int tid = threadIdx.x;

    __shared__ float Woc[32][33];
    __shared__ float ys[32];
    for (int i = tid; i < 1024; i += 256) {
        int o = i >> 5, r = i & 31;
        Woc[o][r] = Wo[(c * 32 + o) * 32 + r];
    }
    if (tid < 32) ys[tid] = Y[((long)b * 1025 + 1024) * 2048 + c * 32 + tid];
    __syncthreads();

    const int r = tid & 31;
    const int rgrp = tid >> 5;
    const float bor = bo[c * 32 + r];
    for (int it = 0; it < 8; ++it) {
        int bl = bl0 + it * 8 + rgrp;
        int l = bl & 1023;
        const float* yp = &Y[((long)b * 1025 + l) * 2048 + c * 32];
        float acc = bor;
        #pragma unroll
        for (int o = 0; o < 32; ++o) acc += (yp[o] + ys[o]) * Woc[o][r];
        long oi = (long)bl * 2048 + c * 32 + r;
        out[oi] = x[oi] + acc;
    }
}

// ---------------------------------------------------------------------------
extern "C" void kernel_launch(void* const* d_in, const int* in_sizes, int n_in,
                              void* d_out, int out_size, void* d_ws, size_t ws_size,
                              hipStream_t stream)
{
    const float* x  = (const float*)d_in[0];
    const float* Wq = (const float*)d_in[1];
    const float* bq = (const float*)d_in[2];
    const float* Wk = (const float*)d_in[3];
    const float* bk = (const float*)d_in[4];
    const float* Wv = (const float*)d_in[5];
    const float* bv = (const float*)d_in[6];
    const float* Wo = (const float*)d_in[7];
    const float* bo = (const float*)d_in[8];
    const float* sq = (const float*)d_in[9];
    float* out = (float*)d_out;

    // workspace layout (float units); Y aliases the xb/Wt/bias region
    float* ws = (float*)d_ws;
    float* qk    = ws;                         // 2048*576          = 1,179,648
    float* P     = qk + 1179648;               // 2*1025*1024       = 2,099,200
    short* vt    = (short*)(P + 2099200);      // 2*2048*1024 bf16  = 2,097,152 f32
    float* region = P + 2099200 + 2097152;     // shared region
    short* xb    = (short*)region;             // 2048*2048 bf16    = 2,097,152 f32
    short* Wt    = (short*)(region + 2097152); // 576*2048 bf16     =   589,824 f32
    float* biasqk = region + 2097152 + 589824; // 576
    float* Y     = region;                     // 2*1025*2048       = 4,198,400 (aliases xb/Wt/bias)
    // total = 1,179,648 + 2,099,200 + 2,097,152 + 4,198,400 floats ~= 38.3 MB

    dim3 blk(256);

    // x -> bf16
    convert_x_kernel<<<dim3(4096), blk, 0, stream>>>(x, xb, 1048576);
    // [Wq|Wk] -> transposed bf16 Wt[576][2048]
    convert_w_kernel<<<dim3(9, 32), blk, 0, stream>>>(Wq, Wk, Wt);
    bias_fuse_kernel<<<dim3(1), dim3(576), 0, stream>>>(bq, bk, biasqk);
    // fused qk projection: (2048x2048)@(2048x576) bf16 MFMA
    mfma_gemm_kernel<false><<<dim3(9, 32, 1), blk, 0, stream>>>(
        xb, 2048, 0, Wt, 2048, 0, biasqk, qk, 576, 0, 2048, 576, 2048);
    // v projection -> transposed bf16 vt[b][co][l]
    vproj_kernel<<<dim3(64, 32), blk, 0, stream>>>(x, Wv, bv, vt);
    // head-averaged attention rows (fp32)
    attn_kernel<<<dim3(2048), blk, 0, stream>>>(qk, P);
    // sink rows
    hipMemsetAsync(P + (long)1024 * 1024, 0, 1024 * sizeof(float), stream);
    hipMemsetAsync(P + (long)2049 * 1024, 0, 1024 * sizeof(float), stream);
    sink_kernel<<<dim3(64), blk, 0, stream>>>(sq, qk, P);
    // Y = P_ext @ v : per batch (1025x1024)@(1024x2048), A fp32-converted
    mfma_gemm_kernel<true><<<dim3(32, 17, 2), blk, 0, stream>>>(
        P, 1024, (long)1025 * 1024, vt, 1024, (long)2048 * 1024, nullptr,
        Y, 2048, (long)1025 * 2048, 1025, 2048, 1024);
    // epilogue
    out_kernel<<<dim3(64, 32), blk, 0, stream>>>(x, Y, Wo, bo, out);
}

// Round 3
// 298.528 us; speedup vs baseline: 3.7265x; 1.4189x over previous
//
#include <hip/hip_runtime.h>
#include <hip/hip_bf16.h>
#include <math.h>

// B=2, L=1024, C=64, R=32, RV=32, DQK=64, H=8, NSINK=4
// x: (2,1024,64,32) fp32; out same. BL = 2048.

typedef __attribute__((ext_vector_type(8))) short short8;
typedef __attribute__((ext_vector_type(4))) short short4v;
typedef __attribute__((ext_vector_type(4))) float float4v;

__device__ __forceinline__ short f2b(float f) {
    __hip_bfloat16 h = __float2bfloat16(f);
    return __builtin_bit_cast(short, h);
}
__device__ __forceinline__ float b2f(short s) {
    unsigned u = ((unsigned)(unsigned short)s) << 16;
    return __builtin_bit_cast(float, u);
}

// ---------------------------------------------------------------------------
// Build transposed bf16 weight Wt[n][k], n in [0,576): col n<512 from Wq
// (2048x512), else from Wk (2048x64). grid (9, 32): (n-tile, k-tile)
// ---------------------------------------------------------------------------
__global__ __launch_bounds__(256) void convert_w_kernel(
    const float* __restrict__ Wq, const float* __restrict__ Wk,
    short* __restrict__ Wt)
{
    const int n0 = blockIdx.x * 64;
    const int k0 = blockIdx.y * 64;
    const int tid = threadIdx.x;
    __shared__ float ts[64][65];
    for (int i = tid; i < 4096; i += 256) {
        int kk = i >> 6, nn = i & 63;
        int n = n0 + nn, k = k0 + kk;
        float v = (n < 512) ? Wq[(long)k * 512 + n] : Wk[(long)k * 64 + (n - 512)];
        ts[kk][nn] = v;
    }
    __syncthreads();
    for (int i = tid; i < 4096; i += 256) {
        int nn = i >> 6, kk = i & 63;
        Wt[(long)(n0 + nn) * 2048 + k0 + kk] = f2b(ts[kk][nn]);
    }
}

__global__ void bias_fuse_kernel(const float* __restrict__ bq,
                                 const float* __restrict__ bk,
                                 float* __restrict__ biasqk)
{
    int t = threadIdx.x;   // block of 576
    biasqk[t] = (t < 512) ? bq[t] : bk[t - 512];
}

// ---------------------------------------------------------------------------
// bf16 MFMA GEMM: C[M,N] fp32 = A[M,K] @ Bt[N,K]^T (+bias). A bf16 or fp32
// (converted during staging). 64x64 tile, 4 waves 2x2, 16x16x32 MFMA.
// ---------------------------------------------------------------------------
template <bool AF32>
__global__ __launch_bounds__(256) void mfma_gemm_kernel(
    const void* __restrict__ Aptr, int lda, long sA,
    const short* __restrict__ Bt, int ldb, long sB,
    const float* __restrict__ bias,
    float* __restrict__ Cm, int ldc, long sC,
    int M, int N, int K)
{
    const short* Ab = (const short*)Aptr;
    const float* Af = (const float*)Aptr;
    Ab += (long)blockIdx.z * sA;
    Af += (long)blockIdx.z * sA;
    const short* Bz = Bt + (long)blockIdx.z * sB;
    float* Cz = Cm + (long)blockIdx.z * sC;

    __shared__ short As[64][72];
    __shared__ short Bs[64][72];

    const int tid = threadIdx.x;
    const int wave = tid >> 6;
    const int lane = tid & 63;
    const int wm = wave >> 1, wn = wave & 1;
    const int m15 = lane & 15;
    const int quad = lane >> 4;
    const int row0 = blockIdx.y * 64;
    const int col0 = blockIdx.x * 64;

    float4v acc[2][2];
    #pragma unroll
    for (int i = 0; i < 2; ++i)
        #pragma unroll
        for (int j = 0; j < 2; ++j)
            #pragma unroll
            for (int r = 0; r < 4; ++r) acc[i][j][r] = 0.f;

    for (int k0 = 0; k0 < K; k0 += 64) {
        if (AF32) {
            #pragma unroll
            for (int p = 0; p < 4; ++p) {
                int i = tid + p * 256;
                int m = i >> 4, kq = i & 15;
                int rr = row0 + m;
                float4 v = {0.f, 0.f, 0.f, 0.f};
                if (rr < M) v = *reinterpret_cast<const float4*>(&Af[(long)rr * lda + k0 + kq * 4]);
                short4v o;
                o[0] = f2b(v.x); o[1] = f2b(v.y); o[2] = f2b(v.z); o[3] = f2b(v.w);
                *reinterpret_cast<short4v*>(&As[m][kq * 4]) = o;
            }
        } else {
            #pragma unroll
            for (int p = 0; p < 2; ++p) {
                int i = tid + p * 256;
                int m = i >> 3, kq = i & 7;
                int rr = row0 + m;
                short8 v = {0, 0, 0, 0, 0, 0, 0, 0};
                if (rr < M) v = *reinterpret_cast<const short8*>(&Ab[(long)rr * lda + k0 + kq * 8]);
                *reinterpret_cast<short8*>(&As[m][kq * 8]) = v;
            }
        }
        #pragma unroll
        for (int p = 0; p < 2; ++p) {
            int i = tid + p * 256;
            int n = i >> 3, kq = i & 7;
            short8 v = *reinterpret_cast<const short8*>(&Bz[(long)(col0 + n) * ldb + k0 + kq * 8]);
            *reinterpret_cast<short8*>(&Bs[n][kq * 8]) = v;
        }
        __syncthreads();

        #pragma unroll
        for (int ks = 0; ks < 2; ++ks) {
            short8 a[2], b[2];
            #pragma unroll
            for (int t = 0; t < 2; ++t) {
                a[t] = *reinterpret_cast<const short8*>(&As[wm * 32 + t * 16 + m15][ks * 32 + quad * 8]);
                b[t] = *reinterpret_cast<const short8*>(&Bs[wn * 32 + t * 16 + m15][ks * 32 + quad * 8]);
            }
            #pragma unroll
            for (int ti = 0; ti < 2; ++ti)
                #pragma unroll
                for (int tj = 0; tj < 2; ++tj)
                    acc[ti][tj] = __builtin_amdgcn_mfma_f32_16x16x32_bf16(
                        a[ti], b[tj], acc[ti][tj], 0, 0, 0);
        }
        __syncthreads();
    }

    #pragma unroll
    for (int ti = 0; ti < 2; ++ti) {
        #pragma unroll
        for (int r = 0; r < 4; ++r) {
            int row = row0 + wm * 32 + ti * 16 + quad * 4 + r;
            if (row >= M) continue;
            #pragma unroll
            for (int tj = 0; tj < 2; ++tj) {
                int col = col0 + wn * 32 + tj * 16 + m15;
                float vv = acc[ti][tj][r];
                if (bias) vv += bias[col];
                Cz[(long)row * ldc + col] = vv;
            }
        }
    }
}

// ---------------------------------------------------------------------------
// QK^T via MFMA, all 8 heads per block. Per batch b:
//   S[h, l, s] (bf16) = 0.125 * sum_d q[l, h*64+d] * k[s, d]
// q,k read from qk buffer (ld 576, k at col 512). grid (16 s-tiles, 16 l-tiles).
// ---------------------------------------------------------------------------
__global__ __launch_bounds__(256) void qk_s_kernel(
    const float* __restrict__ qk, short* __restrict__ S, int b)
{
    const int s0 = blockIdx.x * 64;
    const int l0 = blockIdx.y * 64;
    const int tid = threadIdx.x;

    __shared__ short Qs[64][520];   // 64 l x 512 d (+8 pad)
    __shared__ short Ks[64][72];    // 64 s x 64 d  (+8 pad)

    // stage q tile: 64 rows x 512 floats = 8192 float4
    #pragma unroll
    for (int p = 0; p < 32; ++p) {
        int i = tid + p * 256;
        int row = i >> 7, d4 = i & 127;
        float4 v = *reinterpret_cast<const float4*>(
            &qk[(long)((b << 10) + l0 + row) * 576 + d4 * 4]);
        short4v o;
        o[0] = f2b(v.x); o[1] = f2b(v.y); o[2] = f2b(v.z); o[3] = f2b(v.w);
        *reinterpret_cast<short4v*>(&Qs[row][d4 * 4]) = o;
    }
    // stage k tile: 64 rows x 64 floats = 1024 float4
    #pragma unroll
    for (int p = 0; p < 4; ++p) {
        int i = tid + p * 256;
        int row = i >> 4, d4 = i & 15;
        float4 v = *reinterpret_cast<const float4*>(
            &qk[(long)((b << 10) + s0 + row) * 576 + 512 + d4 * 4]);
        short4v o;
        o[0] = f2b(v.x); o[1] = f2b(v.y); o[2] = f2b(v.z); o[3] = f2b(v.w);
        *reinterpret_cast<short4v*>(&Ks[row][d4 * 4]) = o;
    }
    __syncthreads();

    const int wave = tid >> 6;
    const int lane = tid & 63;
    const int wm = wave >> 1, wn = wave & 1;
    const int m15 = lane & 15;
    const int quad = lane >> 4;

    for (int h = 0; h < 8; ++h) {
        float4v acc[2][2];
        #pragma unroll
        for (int i = 0; i < 2; ++i)
            #pragma unroll
            for (int j = 0; j < 2; ++j)
                #pragma unroll
                for (int r = 0; r < 4; ++r) acc[i][j][r] = 0.f;

        #pragma unroll
        for (int ks = 0; ks < 2; ++ks) {
            short8 a[2], bfr[2];
            #pragma unroll
            for (int t = 0; t < 2; ++t) {
                a[t]   = *reinterpret_cast<const short8*>(
                    &Qs[wm * 32 + t * 16 + m15][h * 64 + ks * 32 + quad * 8]);
                bfr[t] = *reinterpret_cast<const short8*>(
                    &Ks[wn * 32 + t * 16 + m15][ks * 32 + quad * 8]);
            }
            #pragma unroll
            for (int ti = 0; ti < 2; ++ti)
                #pragma unroll
                for (int tj = 0; tj < 2; ++tj)
                    acc[ti][tj] = __builtin_amdgcn_mfma_f32_16x16x32_bf16(
                        a[ti], bfr[tj], acc[ti][tj], 0, 0, 0);
        }

        #pragma unroll
        for (int ti = 0; ti < 2; ++ti)
            #pragma unroll
            for (int r = 0; r < 4; ++r) {
                int l = l0 + wm * 32 + ti * 16 + quad * 4 + r;
                #pragma unroll
                for (int tj = 0; tj < 2; ++tj) {
                    int s = s0 + wn * 32 + tj * 16 + m15;
                    S[((long)h << 20) + (l << 10) + s] = f2b(acc[ti][tj][r] * 0.125f);
                }
            }
    }
}

// ---------------------------------------------------------------------------
// Per-row softmax over s for 8 heads + head-average: P[b,l,s] (fp32).
// Block per l (1024 blocks per batch). Thread (h = tid>>5, j = tid&31) owns
// s = i*32+j, i<32.
// ---------------------------------------------------------------------------
__global__ __launch_bounds__(256) void softmax_avg_kernel(
    const short* __restrict__ S, float* __restrict__ P, int b)
{
    const int l = blockIdx.x;
    const int tid = threadIdx.x;
    const int h = tid >> 5, j = tid & 31;

    __shared__ float es[8][1032];
    __shared__ float invd[8];

    const short* row = &S[((long)h << 20) + (l << 10)];
    float vals[32];
    float pm = -1e30f;
    #pragma unroll
    for (int i = 0; i < 32; ++i) {
        float f = b2f(row[i * 32 + j]);
        vals[i] = f;
        pm = fmaxf(pm, f);
    }
    #pragma unroll
    for (int off = 16; off > 0; off >>= 1) pm = fmaxf(pm, __shfl_down(pm, off, 32));
    pm = __shfl(pm, 0, 32);

    float ps = 0.f;
    #pragma unroll
    for (int i = 0; i < 32; ++i) {
        float e = __expf(vals[i] - pm);
        vals[i] = e;
        ps += e;
    }
    #pragma unroll
    for (int off = 16; off > 0; off >>= 1) ps += __shfl_down(ps, off, 32);
    if (j == 0) invd[h] = 1.f / (8.f * ps);
    __syncthreads();

    const float w = invd[h];
    #pragma unroll
    for (int i = 0; i < 32; ++i) es[h][i * 32 + j] = vals[i] * w;
    __syncthreads();

    for (int s = tid; s < 1024; s += 256) {
        float p = 0.f;
        #pragma unroll
        for (int hh = 0; hh < 8; ++hh) p += es[hh][s];
        P[((long)b * 1025 + l) * 1024 + s] = p;
    }
}

// ---------------------------------------------------------------------------
// Per-channel value projection, writes TRANSPOSED bf16: vt[b][c*32+o][l]
// ---------------------------------------------------------------------------
__global__ __launch_bounds__(256) void vproj_kernel(
    const float* __restrict__ x, const float* __restrict__ Wv,
    const float* __restrict__ bv, short* __restrict__ vt)
{
    const int c = blockIdx.x;
    const int chunk = blockIdx.y;       // 0..31
    const int b = chunk >> 4;
    const int l0 = (chunk & 15) * 64;
    const int tid = threadIdx.x;
    __shared__ float Wc[32][33];
    __shared__ float xs[64][33];
    for (int i = tid; i < 1024; i += 256)
        Wc[i >> 5][i & 31] = Wv[(c * 32 + (i >> 5)) * 32 + (i & 31)];
    for (int i = tid; i < 2048; i += 256) {
        int s = i >> 5, r = i & 31;
        xs[s][r] = x[((long)(b << 10) + l0 + s) * 2048 + c * 32 + r];
    }
    __syncthreads();
    const int s = tid & 63;
    const int og = tid >> 6;
    #pragma unroll
    for (int oi = 0; oi < 8; ++oi) {
        int o = og * 8 + oi;
        float acc = bv[c * 32 + o];
        #pragma unroll
        for (int r = 0; r < 32; ++r) acc += xs[s][r] * Wc[r][o];
        vt[(long)b * (2048 * 1024) + (long)(c * 32 + o) * 1024 + l0 + s] = f2b(acc);
    }
}

// ---------------------------------------------------------------------------
// Sink branch -> atomicAdd into P row 1024 per batch (pre-zeroed).
// ---------------------------------------------------------------------------
__global__ __launch_bounds__(256) void sink_kernel(
    const float* __restrict__ sink_q, const float* __restrict__ qk,
    float* __restrict__ P)
{
    const int z = blockIdx.x;
    const int b = z >> 5;
    const int idx = z & 31;
    const int tid = threadIdx.x;

    __shared__ float sq[64];
    __shared__ float lgl[1024];
    __shared__ float red[4];
    __shared__ float mxs, invs;

    if (tid < 64) sq[tid] = sink_q[idx * 64 + tid];
    __syncthreads();

    float lmax = -1e30f;
    for (int l = tid; l < 1024; l += 256) {
        const float4* kp = reinterpret_cast<const float4*>(&qk[((long)(b << 10) + l) * 576 + 512]);
        const float4* sp = reinterpret_cast<const float4*>(sq);
        float acc = 0.f;
        #pragma unroll
        for (int d4 = 0; d4 < 16; ++d4) {
            float4 kv = kp[d4];
            float4 sv = sp[d4];
            acc += kv.x * sv.x + kv.y * sv.y + kv.z * sv.z + kv.w * sv.w;
        }
        acc *= 0.125f;
        lgl[l] = acc;
        lmax = fmaxf(lmax, acc);
    }
    #pragma unroll
    for (int off = 32; off > 0; off >>= 1) lmax = fmaxf(lmax, __shfl_down(lmax, off, 64));
    if ((tid & 63) == 0) red[tid >> 6] = lmax;
    __syncthreads();
    if (tid == 0) mxs = fmaxf(fmaxf(red[0], red[1]), fmaxf(red[2], red[3]));
    __syncthreads();

    const float m = mxs;
    float psum = 0.f;
    for (int l = tid; l < 1024; l += 256) {
        float e = __expf(lgl[l] - m);
        lgl[l] = e;
        psum += e;
    }
    #pragma unroll
    for (int off = 32; off > 0; off >>= 1) psum += __shfl_down(psum, off, 64);
    if ((tid & 63) == 0) red[tid >> 6] = psum;
    __syncthreads();
    if (tid == 0) invs = 1.f / (red[0] + red[1] + red[2] + red[3]);
    __syncthreads();

    const float wgt = invs * (1.f / 32.f);
    float* Prow = &P[((long)b * 1025 + 1024) * 1024];
    for (int l = tid; l < 1024; l += 256) {
        atomicAdd(&Prow[l], lgl[l] * wgt);
    }
}

// ---------------------------------------------------------------------------
// out[bl,c,r] = x + bo + sum_o (Y[b,l,c,o] + Y[b,1024,c,o]) * Wo[c,o,r]
// ---------------------------------------------------------------------------
__global__ __launch_bounds__(256) void out_kernel(
    const float* __restrict__ x, const float* __restrict__ Y,
    const float* __restrict__ Wo, const float* __restrict__ bo,
    float* __restrict__ out)
{
    const int c = blockIdx.x;
    const int bl0 = blockIdx.y * 64;
    const int b = bl0 >> 10;
    const int tid = threadIdx.x;

    __shared__ float Woc[32][33];
    __shared__ float ys[32];
    for (int i = tid; i < 1024; i += 256) {
        int o = i >> 5, r = i & 31;
        Woc[o][r] = Wo[(c * 32 + o) * 32 + r];
    }
    if (tid < 32) ys[tid] = Y[((long)b * 1025 + 1024) * 2048 + c * 32 + tid];
    __syncthreads();

    const int r = tid & 31;
    const int rgrp = tid >> 5;
    const float bor = bo[c * 32 + r];
    for (int it = 0; it < 8; ++it) {
        int bl = bl0 + it * 8 + rgrp;
        int l = bl & 1023;
        const float* yp = &Y[((long)b * 1025 + l) * 2048 + c * 32];
        float acc = bor;
        #pragma unroll
        for (int o = 0; o < 32; ++o) acc += (yp[o] + ys[o]) * Woc[o][r];
        long oi = (long)bl * 2048 + c * 32 + r;
        out[oi] = x[oi] + acc;
    }
}

// ---------------------------------------------------------------------------
extern "C" void kernel_launch(void* const* d_in, const int* in_sizes, int n_in,
                              void* d_out, int out_size, void* d_ws, size_t ws_size,
                              hipStream_t stream)
{
    const float* x  = (const float*)d_in[0];
    const float* Wq = (const float*)d_in[1];
    const float* bq = (const float*)d_in[2];
    const float* Wk = (const float*)d_in[3];
    const float* bk = (const float*)d_in[4];
    const float* Wv = (const float*)d_in[5];
    const float* bv = (const float*)d_in[6];
    const float* Wo = (const float*)d_in[7];
    const float* bo = (const float*)d_in[8];
    const float* sq = (const float*)d_in[9];
    float* out = (float*)d_out;

    // workspace layout (float units); region shared sequentially by
    // {Wt+biasqk} -> {S (per-batch)} -> {Y}
    float* ws = (float*)d_ws;
    float* qk     = ws;                          // 2048*576          = 1,179,648
    float* P      = qk + 1179648;                // 2*1025*1024       = 2,099,200
    short* vt     = (short*)(P + 2099200);       // 2*2048*1024 bf16  = 2,097,152 f32
    float* region = P + 2099200 + 2097152;
    short* Wt     = (short*)region;              // 576*2048 bf16     =   589,824 f32
    float* biasqk = region + 589824;             // 576
    short* Sb     = (short*)region;              // 8*1024*1024 bf16  = 4,194,304 f32
    float* Y      = region;                      // 2*1025*2048       = 4,198,400
    // total = 9,574,400 floats ~= 38.3 MB

    dim3 blk(256);

    // [Wq|Wk] -> transposed bf16 Wt[576][2048]
    convert_w_kernel<<<dim3(9, 32), blk, 0, stream>>>(Wq, Wk, Wt);
    bias_fuse_kernel<<<dim3(1), dim3(576), 0, stream>>>(bq, bk, biasqk);
    // fused qk projection: (2048x2048)@(2048x576), A = x fp32 staged->bf16
    mfma_gemm_kernel<true><<<dim3(9, 32, 1), blk, 0, stream>>>(
        x, 2048, 0, Wt, 2048, 0, biasqk, qk, 576, 0, 2048, 576, 2048);
    // v projection -> transposed bf16 vt[b][co][l]
    vproj_kernel<<<dim3(64, 32), blk, 0, stream>>>(x, Wv, bv, vt);
    // attention: per batch, S = QK^T (MFMA, bf16), then softmax+head-avg -> P
    for (int b = 0; b < 2; ++b) {
        qk_s_kernel<<<dim3(16, 16), blk, 0, stream>>>(qk, Sb, b);
        softmax_avg_kernel<<<dim3(1024), blk, 0, stream>>>(Sb, P, b);
    }
    // sink rows
    hipMemsetAsync(P + (long)1024 * 1024, 0, 1024 * sizeof(float), stream);
    hipMemsetAsync(P + (long)2049 * 1024, 0, 1024 * sizeof(float), stream);
    sink_kernel<<<dim3(64), blk, 0, stream>>>(sq, qk, P);
    // Y = P_ext @ v : per batch (1025x1024)@(1024x2048), A fp32-converted
    mfma_gemm_kernel<true><<<dim3(32, 17, 2), blk, 0, stream>>>(
        P, 1024, (long)1025 * 1024, vt, 1024, (long)2048 * 1024, nullptr,
        Y, 2048, (long)1025 * 2048, 1025, 2048, 1024);
    // epilogue
    out_kernel<<<dim3(64, 32), blk, 0, stream>>>(x, Y, Wo, bo, out);
}

// Round 4
// 263.410 us; speedup vs baseline: 4.2233x; 1.1333x over previous
//
#include <hip/hip_runtime.h>
#include <hip/hip_bf16.h>
#include <math.h>

// B=2, L=1024, C=64, R=32, RV=32, DQK=64, H=8, NSINK=4
// x: (2,1024,64,32) fp32; out same. BL = 2048.

typedef __attribute__((ext_vector_type(8))) short short8;
typedef __attribute__((ext_vector_type(4))) short short4v;
typedef __attribute__((ext_vector_type(4))) float float4v;

__device__ __forceinline__ short f2b(float f) {
    __hip_bfloat16 h = __float2bfloat16(f);
    return __builtin_bit_cast(short, h);
}
__device__ __forceinline__ float b2f(short s) {
    unsigned u = ((unsigned)(unsigned short)s) << 16;
    return __builtin_bit_cast(float, u);
}

// ---------------------------------------------------------------------------
// x (fp32) -> xb (bf16), n4 = elems/4
// ---------------------------------------------------------------------------
__global__ __launch_bounds__(256) void convert_x_kernel(
    const float* __restrict__ src, short* __restrict__ dst, int n4)
{
    int id = blockIdx.x * 256 + threadIdx.x;
    if (id >= n4) return;
    float4 v = reinterpret_cast<const float4*>(src)[id];
    short4v o;
    o[0] = f2b(v.x); o[1] = f2b(v.y); o[2] = f2b(v.z); o[3] = f2b(v.w);
    reinterpret_cast<short4v*>(dst)[id] = o;
}

// ---------------------------------------------------------------------------
// [Wq|Wk] -> transposed bf16 Wt[576][2048]. grid (9 n-tiles, 32 k-tiles)
// ---------------------------------------------------------------------------
__global__ __launch_bounds__(256) void convert_w_kernel(
    const float* __restrict__ Wq, const float* __restrict__ Wk,
    short* __restrict__ Wt)
{
    const int n0 = blockIdx.x * 64;
    const int k0 = blockIdx.y * 64;
    const int tid = threadIdx.x;
    __shared__ float ts[64][65];
    for (int i = tid; i < 4096; i += 256) {
        int kk = i >> 6, nn = i & 63;
        int n = n0 + nn, k = k0 + kk;
        float v = (n < 512) ? Wq[(long)k * 512 + n] : Wk[(long)k * 64 + (n - 512)];
        ts[kk][nn] = v;
    }
    __syncthreads();
    for (int i = tid; i < 4096; i += 256) {
        int nn = i >> 6, kk = i & 63;
        Wt[(long)(n0 + nn) * 2048 + k0 + kk] = f2b(ts[kk][nn]);
    }
}

// ---------------------------------------------------------------------------
// qk[row][n] = bias (bq|bk), row-per-block. Split-K GEMM accumulates on top.
// ---------------------------------------------------------------------------
__global__ __launch_bounds__(256) void bias_init_kernel(
    const float* __restrict__ bq, const float* __restrict__ bk,
    float* __restrict__ qk)
{
    const int row = blockIdx.x;
    for (int n = threadIdx.x; n < 576; n += 256)
        qk[(long)row * 576 + n] = (n < 512) ? bq[n] : bk[n - 512];
}

// ---------------------------------------------------------------------------
// qk projection, split-K=2: qk[2048][576] += xb[2048][2048] @ Wt[576][2048]^T
// 64x64 tile, 4 waves 2x2, 16x16x32 bf16 MFMA, fp32 atomicAdd epilogue.
// grid (9, 32, 2)
// ---------------------------------------------------------------------------
__global__ __launch_bounds__(256) void qkproj_kernel(
    const short* __restrict__ xb, const short* __restrict__ Wt,
    float* __restrict__ qk)
{
    __shared__ short As[64][72];
    __shared__ short Bs[64][72];

    const int tid = threadIdx.x;
    const int wave = tid >> 6;
    const int lane = tid & 63;
    const int wm = wave >> 1, wn = wave & 1;
    const int m15 = lane & 15;
    const int quad = lane >> 4;
    const int row0 = blockIdx.y * 64;
    const int col0 = blockIdx.x * 64;
    const int kbase = blockIdx.z * 1024;

    float4v acc[2][2];
    #pragma unroll
    for (int i = 0; i < 2; ++i)
        #pragma unroll
        for (int j = 0; j < 2; ++j)
            #pragma unroll
            for (int r = 0; r < 4; ++r) acc[i][j][r] = 0.f;

    for (int kt = 0; kt < 16; ++kt) {
        int k0 = kbase + kt * 64;
        #pragma unroll
        for (int p = 0; p < 2; ++p) {
            int i = tid + p * 256;
            int m = i >> 3, kq = i & 7;
            *reinterpret_cast<short8*>(&As[m][kq * 8]) =
                *reinterpret_cast<const short8*>(&xb[(long)(row0 + m) * 2048 + k0 + kq * 8]);
        }
        #pragma unroll
        for (int p = 0; p < 2; ++p) {
            int i = tid + p * 256;
            int n = i >> 3, kq = i & 7;
            *reinterpret_cast<short8*>(&Bs[n][kq * 8]) =
                *reinterpret_cast<const short8*>(&Wt[(long)(col0 + n) * 2048 + k0 + kq * 8]);
        }
        __syncthreads();
        #pragma unroll
        for (int ks = 0; ks < 2; ++ks) {
            short8 a[2], b[2];
            #pragma unroll
            for (int t = 0; t < 2; ++t) {
                a[t] = *reinterpret_cast<const short8*>(&As[wm * 32 + t * 16 + m15][ks * 32 + quad * 8]);
                b[t] = *reinterpret_cast<const short8*>(&Bs[wn * 32 + t * 16 + m15][ks * 32 + quad * 8]);
            }
            #pragma unroll
            for (int ti = 0; ti < 2; ++ti)
                #pragma unroll
                for (int tj = 0; tj < 2; ++tj)
                    acc[ti][tj] = __builtin_amdgcn_mfma_f32_16x16x32_bf16(
                        a[ti], b[tj], acc[ti][tj], 0, 0, 0);
        }
        __syncthreads();
    }

    #pragma unroll
    for (int ti = 0; ti < 2; ++ti)
        #pragma unroll
        for (int r = 0; r < 4; ++r) {
            int row = row0 + wm * 32 + ti * 16 + quad * 4 + r;
            #pragma unroll
            for (int tj = 0; tj < 2; ++tj) {
                int col = col0 + wn * 32 + tj * 16 + m15;
                atomicAdd(&qk[(long)row * 576 + col], acc[ti][tj][r]);
            }
        }
}

// ---------------------------------------------------------------------------
// qk fp32 -> qkb bf16 (1,179,648 elems). grid 1152.
// ---------------------------------------------------------------------------
__global__ __launch_bounds__(256) void convert_qk_kernel(
    const float* __restrict__ qk, short* __restrict__ qkb)
{
    int id = blockIdx.x * 256 + threadIdx.x;   // < 294912
    float4 v = reinterpret_cast<const float4*>(qk)[id];
    short4v o;
    o[0] = f2b(v.x); o[1] = f2b(v.y); o[2] = f2b(v.z); o[3] = f2b(v.w);
    reinterpret_cast<short4v*>(qkb)[id] = o;
}

// ---------------------------------------------------------------------------
// QK^T via MFMA, all 8 heads, bf16 in. S[h,l,s] bf16 per batch b.
// grid (16 s-tiles, 16 l-tiles)
// ---------------------------------------------------------------------------
__global__ __launch_bounds__(256) void qk_s_kernel(
    const short* __restrict__ qkb, short* __restrict__ S, int b)
{
    const int s0 = blockIdx.x * 64;
    const int l0 = blockIdx.y * 64;
    const int tid = threadIdx.x;

    __shared__ short Qs[64][520];   // 64 l x 512 d (+8 pad)
    __shared__ short Ks[64][72];    // 64 s x 64 d  (+8 pad)

    #pragma unroll
    for (int p = 0; p < 16; ++p) {
        int i = tid + p * 256;
        int row = i >> 6, d8 = i & 63;
        *reinterpret_cast<short8*>(&Qs[row][d8 * 8]) =
            *reinterpret_cast<const short8*>(&qkb[(long)((b << 10) + l0 + row) * 576 + d8 * 8]);
    }
    #pragma unroll
    for (int p = 0; p < 2; ++p) {
        int i = tid + p * 256;
        int row = i >> 3, d8 = i & 7;
        *reinterpret_cast<short8*>(&Ks[row][d8 * 8]) =
            *reinterpret_cast<const short8*>(&qkb[(long)((b << 10) + s0 + row) * 576 + 512 + d8 * 8]);
    }
    __syncthreads();

    const int wave = tid >> 6;
    const int lane = tid & 63;
    const int wm = wave >> 1, wn = wave & 1;
    const int m15 = lane & 15;
    const int quad = lane >> 4;

    for (int h = 0; h < 8; ++h) {
        float4v acc[2][2];
        #pragma unroll
        for (int i = 0; i < 2; ++i)
            #pragma unroll
            for (int j = 0; j < 2; ++j)
                #pragma unroll
                for (int r = 0; r < 4; ++r) acc[i][j][r] = 0.f;

        #pragma unroll
        for (int ks = 0; ks < 2; ++ks) {
            short8 a[2], bfr[2];
            #pragma unroll
            for (int t = 0; t < 2; ++t) {
                a[t]   = *reinterpret_cast<const short8*>(
                    &Qs[wm * 32 + t * 16 + m15][h * 64 + ks * 32 + quad * 8]);
                bfr[t] = *reinterpret_cast<const short8*>(
                    &Ks[wn * 32 + t * 16 + m15][ks * 32 + quad * 8]);
            }
            #pragma unroll
            for (int ti = 0; ti < 2; ++ti)
                #pragma unroll
                for (int tj = 0; tj < 2; ++tj)
                    acc[ti][tj] = __builtin_amdgcn_mfma_f32_16x16x32_bf16(
                        a[ti], bfr[tj], acc[ti][tj], 0, 0, 0);
        }

        #pragma unroll
        for (int ti = 0; ti < 2; ++ti)
            #pragma unroll
            for (int r = 0; r < 4; ++r) {
                int l = l0 + wm * 32 + ti * 16 + quad * 4 + r;
                #pragma unroll
                for (int tj = 0; tj < 2; ++tj) {
                    int s = s0 + wn * 32 + tj * 16 + m15;
                    S[((long)h << 20) + (l << 10) + s] = f2b(acc[ti][tj][r] * 0.125f);
                }
            }
    }
}

// ---------------------------------------------------------------------------
// Softmax over s for 8 heads + head-average -> P bf16 [b][l][s].
// Block per l. Thread (h=tid>>5, j=tid&31) owns s = i*32+j.
// ---------------------------------------------------------------------------
__global__ __launch_bounds__(256) void softmax_avg_kernel(
    const short* __restrict__ S, short* __restrict__ P, int b)
{
    const int l = blockIdx.x;
    const int tid = threadIdx.x;
    const int h = tid >> 5, j = tid & 31;

    __shared__ float es[8][1032];
    __shared__ float invd[8];

    const short* row = &S[((long)h << 20) + (l << 10)];
    float vals[32];
    float pm = -1e30f;
    #pragma unroll
    for (int i = 0; i < 32; ++i) {
        float f = b2f(row[i * 32 + j]);
        vals[i] = f;
        pm = fmaxf(pm, f);
    }
    #pragma unroll
    for (int off = 16; off > 0; off >>= 1) pm = fmaxf(pm, __shfl_down(pm, off, 32));
    pm = __shfl(pm, 0, 32);

    float ps = 0.f;
    #pragma unroll
    for (int i = 0; i < 32; ++i) {
        float e = __expf(vals[i] - pm);
        vals[i] = e;
        ps += e;
    }
    #pragma unroll
    for (int off = 16; off > 0; off >>= 1) ps += __shfl_down(ps, off, 32);
    if (j == 0) invd[h] = 1.f / (8.f * ps);
    __syncthreads();

    const float w = invd[h];
    #pragma unroll
    for (int i = 0; i < 32; ++i) es[h][i * 32 + j] = vals[i] * w;
    __syncthreads();

    for (int s = tid; s < 1024; s += 256) {
        float p = 0.f;
        #pragma unroll
        for (int hh = 0; hh < 8; ++hh) p += es[hh][s];
        P[((long)b << 20) + (l << 10) + s] = f2b(p);
    }
}

// ---------------------------------------------------------------------------
// Per-channel value projection -> TRANSPOSED bf16 vt[b][c*32+o][l]
// ---------------------------------------------------------------------------
__global__ __launch_bounds__(256) void vproj_kernel(
    const float* __restrict__ x, const float* __restrict__ Wv,
    const float* __restrict__ bv, short* __restrict__ vt)
{
    const int c = blockIdx.x;
    const int chunk = blockIdx.y;       // 0..31
    const int b = chunk >> 4;
    const int l0 = (chunk & 15) * 64;
    const int tid = threadIdx.x;
    __shared__ float Wc[32][33];
    __shared__ float xs[64][33];
    for (int i = tid; i < 1024; i += 256)
        Wc[i >> 5][i & 31] = Wv[(c * 32 + (i >> 5)) * 32 + (i & 31)];
    for (int i = tid; i < 2048; i += 256) {
        int s = i >> 5, r = i & 31;
        xs[s][r] = x[((long)(b << 10) + l0 + s) * 2048 + c * 32 + r];
    }
    __syncthreads();
    const int s = tid & 63;
    const int og = tid >> 6;
    #pragma unroll
    for (int oi = 0; oi < 8; ++oi) {
        int o = og * 8 + oi;
        float acc = bv[c * 32 + o];
        #pragma unroll
        for (int r = 0; r < 32; ++r) acc += xs[s][r] * Wc[r][o];
        vt[(long)b * (2048 * 1024) + (long)(c * 32 + o) * 1024 + l0 + s] = f2b(acc);
    }
}

// ---------------------------------------------------------------------------
// Sink: softmax over l of sink_q.k, atomicAdd (1/32)*attn into Psink[b][l].
// grid 64 = (b, h*4+si)
// ---------------------------------------------------------------------------
__global__ __launch_bounds__(256) void sink_kernel(
    const float* __restrict__ sink_q, const short* __restrict__ qkb,
    float* __restrict__ Psink)
{
    const int z = blockIdx.x;
    const int b = z >> 5;
    const int idx = z & 31;
    const int tid = threadIdx.x;

    __shared__ float sq[64];
    __shared__ float lgl[1024];
    __shared__ float red[4];
    __shared__ float mxs, invs;

    if (tid < 64) sq[tid] = sink_q[idx * 64 + tid];
    __syncthreads();

    float lmax = -1e30f;
    for (int l = tid; l < 1024; l += 256) {
        const short* kp = &qkb[(long)((b << 10) + l) * 576 + 512];
        float acc = 0.f;
        #pragma unroll
        for (int d8 = 0; d8 < 8; ++d8) {
            short8 kv = *reinterpret_cast<const short8*>(&kp[d8 * 8]);
            #pragma unroll
            for (int j = 0; j < 8; ++j) acc += b2f(kv[j]) * sq[d8 * 8 + j];
        }
        acc *= 0.125f;
        lgl[l] = acc;
        lmax = fmaxf(lmax, acc);
    }
    #pragma unroll
    for (int off = 32; off > 0; off >>= 1) lmax = fmaxf(lmax, __shfl_down(lmax, off, 64));
    if ((tid & 63) == 0) red[tid >> 6] = lmax;
    __syncthreads();
    if (tid == 0) mxs = fmaxf(fmaxf(red[0], red[1]), fmaxf(red[2], red[3]));
    __syncthreads();

    const float m = mxs;
    float psum = 0.f;
    for (int l = tid; l < 1024; l += 256) {
        float e = __expf(lgl[l] - m);
        lgl[l] = e;
        psum += e;
    }
    #pragma unroll
    for (int off = 32; off > 0; off >>= 1) psum += __shfl_down(psum, off, 64);
    if ((tid & 63) == 0) red[tid >> 6] = psum;
    __syncthreads();
    if (tid == 0) invs = 1.f / (red[0] + red[1] + red[2] + red[3]);
    __syncthreads();

    const float wgt = invs * (1.f / 32.f);
    for (int l = tid; l < 1024; l += 256)
        atomicAdd(&Psink[(b << 10) + l], lgl[l] * wgt);
}

// ---------------------------------------------------------------------------
// Ysink[b][co] = sum_l Psink[b][l] * vt[b][co][l]. grid (512, 2), wave per co.
// ---------------------------------------------------------------------------
__global__ __launch_bounds__(256) void sinky_kernel(
    const float* __restrict__ Psink, const short* __restrict__ vt,
    float* __restrict__ Ysink)
{
    const int b = blockIdx.y;
    const int tid = threadIdx.x;
    __shared__ float ps[1024];
    {
        float4 v = reinterpret_cast<const float4*>(&Psink[b << 10])[tid];
        *reinterpret_cast<float4*>(&ps[tid * 4]) = v;
    }
    __syncthreads();
    const int wave = tid >> 6;
    const int lane = tid & 63;
    const int co = blockIdx.x * 4 + wave;
    const short* vp = &vt[((long)b * 2048 + co) * 1024];
    float acc = 0.f;
    #pragma unroll
    for (int t = 0; t < 16; ++t) {
        int l = t * 64 + lane;
        acc += ps[l] * b2f(vp[l]);
    }
    #pragma unroll
    for (int off = 32; off > 0; off >>= 1) acc += __shfl_down(acc, off, 64);
    if (lane == 0) Ysink[(b << 11) + co] = acc;
}

// ---------------------------------------------------------------------------
// Fused Y-GEMM + output projection:
//  Ytile[64l x 64co] = P[b] @ vt[b]^T  (bf16 MFMA, K=1024)
//  out[bl][cr] = x + bo + sum_o (Yt[l][ch*32+o] + Ysink) * Wo[c][o][r]
// grid (32 co-tiles, 16 l-tiles, 2 b)
// ---------------------------------------------------------------------------
__global__ __launch_bounds__(256) void y_fused_kernel(
    const short* __restrict__ P, const short* __restrict__ vt,
    const float* __restrict__ Ysink, const float* __restrict__ Wo,
    const float* __restrict__ bo, const float* __restrict__ x,
    float* __restrict__ out)
{
    __shared__ union {
        struct { short As[64][72]; short Bs[64][72]; } g;
        struct { float Yt[64][68]; float WoL[2][32][33]; float boL[64]; } e;
    } sm;

    const int tid = threadIdx.x;
    const int b = blockIdx.z;
    const int col0 = blockIdx.x * 64;
    const int row0 = blockIdx.y * 64;
    const short* Pz = P + ((long)b << 20);
    const short* Vz = vt + ((long)b * 2048 * 1024);

    const int wave = tid >> 6;
    const int lane = tid & 63;
    const int wm = wave >> 1, wn = wave & 1;
    const int m15 = lane & 15;
    const int quad = lane >> 4;

    float4v acc[2][2];
    #pragma unroll
    for (int i = 0; i < 2; ++i)
        #pragma unroll
        for (int j = 0; j < 2; ++j)
            #pragma unroll
            for (int r = 0; r < 4; ++r) acc[i][j][r] = 0.f;

    for (int kt = 0; kt < 16; ++kt) {
        int k0 = kt * 64;
        #pragma unroll
        for (int p = 0; p < 2; ++p) {
            int i = tid + p * 256;
            int m = i >> 3, kq = i & 7;
            *reinterpret_cast<short8*>(&sm.g.As[m][kq * 8]) =
                *reinterpret_cast<const short8*>(&Pz[(long)(row0 + m) * 1024 + k0 + kq * 8]);
        }
        #pragma unroll
        for (int p = 0; p < 2; ++p) {
            int i = tid + p * 256;
            int n = i >> 3, kq = i & 7;
            *reinterpret_cast<short8*>(&sm.g.Bs[n][kq * 8]) =
                *reinterpret_cast<const short8*>(&Vz[(long)(col0 + n) * 1024 + k0 + kq * 8]);
        }
        __syncthreads();
        #pragma unroll
        for (int ks = 0; ks < 2; ++ks) {
            short8 a[2], bb[2];
            #pragma unroll
            for (int t = 0; t < 2; ++t) {
                a[t]  = *reinterpret_cast<const short8*>(&sm.g.As[wm * 32 + t * 16 + m15][ks * 32 + quad * 8]);
                bb[t] = *reinterpret_cast<const short8*>(&sm.g.Bs[wn * 32 + t * 16 + m15][ks * 32 + quad * 8]);
            }
            #pragma unroll
            for (int ti = 0; ti < 2; ++ti)
                #pragma unroll
                for (int tj = 0; tj < 2; ++tj)
                    acc[ti][tj] = __builtin_amdgcn_mfma_f32_16x16x32_bf16(
                        a[ti], bb[tj], acc[ti][tj], 0, 0, 0);
        }
        __syncthreads();
    }

    // ---- epilogue: Yt = acc + Ysink; out = x + bo + Yt @ blockdiag(Wo) ----
    float ysv[2];
    #pragma unroll
    for (int tj = 0; tj < 2; ++tj)
        ysv[tj] = Ysink[(b << 11) + col0 + wn * 32 + tj * 16 + m15];

    #pragma unroll
    for (int ti = 0; ti < 2; ++ti)
        #pragma unroll
        for (int r = 0; r < 4; ++r) {
            int row = wm * 32 + ti * 16 + quad * 4 + r;
            #pragma unroll
            for (int tj = 0; tj < 2; ++tj) {
                int col = wn * 32 + tj * 16 + m15;
                sm.e.Yt[row][col] = acc[ti][tj][r] + ysv[tj];
            }
        }
    // stage Wo for the 2 channels and bo
    const int c0 = col0 >> 5;   // first channel
    for (int i = tid; i < 2048; i += 256) {
        int ch = i >> 10, o = (i >> 5) & 31, r = i & 31;
        sm.e.WoL[ch][o][r] = Wo[((long)(c0 + ch) * 32 + o) * 32 + r];
    }
    if (tid < 64) sm.e.boL[tid] = bo[col0 + tid];
    __syncthreads();

    const int row = tid >> 2;           // 0..63
    const int g = tid & 3;              // 16-col group
    const long obase = ((long)(b << 10) + row0 + row) * 2048 + col0 + g * 16;
    float res[16];
    #pragma unroll
    for (int jj = 0; jj < 16; ++jj) {
        int rc = g * 16 + jj;
        int ch = rc >> 5, r = rc & 31;
        float a2 = sm.e.boL[rc];
        #pragma unroll
        for (int o = 0; o < 32; ++o)
            a2 += sm.e.Yt[row][ch * 32 + o] * sm.e.WoL[ch][o][r];
        res[jj] = a2;
    }
    #pragma unroll
    for (int q4 = 0; q4 < 4; ++q4) {
        float4 xv = *reinterpret_cast<const float4*>(&x[obase + q4 * 4]);
        float4 ov;
        ov.x = xv.x + res[q4 * 4 + 0];
        ov.y = xv.y + res[q4 * 4 + 1];
        ov.z = xv.z + res[q4 * 4 + 2];
        ov.w = xv.w + res[q4 * 4 + 3];
        *reinterpret_cast<float4*>(&out[obase + q4 * 4]) = ov;
    }
}

// ---------------------------------------------------------------------------
extern "C" void kernel_launch(void* const* d_in, const int* in_sizes, int n_in,
                              void* d_out, int out_size, void* d_ws, size_t ws_size,
                              hipStream_t stream)
{
    const float* x  = (const float*)d_in[0];
    const float* Wq = (const float*)d_in[1];
    const float* bq = (const float*)d_in[2];
    const float* Wk = (const float*)d_in[3];
    const float* bk = (const float*)d_in[4];
    const float* Wv = (const float*)d_in[5];
    const float* bv = (const float*)d_in[6];
    const float* Wo = (const float*)d_in[7];
    const float* bo = (const float*)d_in[8];
    const float* sq = (const float*)d_in[9];
    float* out = (float*)d_out;

    // workspace layout (float units), total ~36.5 MB
    float* ws = (float*)d_ws;
    float* qk     = ws;                          // 1,179,648 f (2048x576 fp32)
    short* qkb    = (short*)(ws + 1179648);      //   589,824 f (bf16)
    short* P      = (short*)(ws + 1769472);      // 1,048,576 f (2x1024x1024 bf16)
    float* Psink  = ws + 2818048;                //     2,048 f
    short* vt     = (short*)(ws + 2820096);      // 2,097,152 f (bf16)
    float* Ysink  = ws + 4917248;                //     4,096 f
    float* region = ws + 4921344;                // 4,194,304 f shared: {xb,Wt} -> S
    short* xb     = (short*)region;              // 2,097,152 f (bf16)
    short* Wt     = (short*)(region + 2097152);  //   589,824 f (bf16)
    short* Sb     = (short*)region;              // 4,194,304 f (8x1024x1024 bf16)

    dim3 blk(256);

    convert_x_kernel<<<dim3(1024 * 1024 / 256), blk, 0, stream>>>(x, xb, 1048576);
    convert_w_kernel<<<dim3(9, 32), blk, 0, stream>>>(Wq, Wk, Wt);
    bias_init_kernel<<<dim3(2048), blk, 0, stream>>>(bq, bk, qk);
    qkproj_kernel<<<dim3(9, 32, 2), blk, 0, stream>>>(xb, Wt, qk);
    convert_qk_kernel<<<dim3(1152), blk, 0, stream>>>(qk, qkb);
    vproj_kernel<<<dim3(64, 32), blk, 0, stream>>>(x, Wv, bv, vt);
    for (int b = 0; b < 2; ++b) {
        qk_s_kernel<<<dim3(16, 16), blk, 0, stream>>>(qkb, Sb, b);
        softmax_avg_kernel<<<dim3(1024), blk, 0, stream>>>(Sb, P, b);
    }
    hipMemsetAsync(Psink, 0, 2048 * sizeof(float), stream);
    sink_kernel<<<dim3(64), blk, 0, stream>>>(sq, qkb, Psink);
    sinky_kernel<<<dim3(512, 2), blk, 0, stream>>>(Psink, vt, Ysink);
    y_fused_kernel<<<dim3(32, 16, 2), blk, 0, stream>>>(
        P, vt, Ysink, Wo, bo, x, out);
}

// Round 5
// 207.670 us; speedup vs baseline: 5.3569x; 1.2684x over previous
//
#include <hip/hip_runtime.h>
#include <hip/hip_bf16.h>
#include <math.h>

// B=2, L=1024, C=64, R=32, RV=32, DQK=64, H=8, NSINK=4
// x: (2,1024,64,32) fp32; out same. BL = 2048.

typedef __attribute__((ext_vector_type(8))) short short8;
typedef __attribute__((ext_vector_type(4))) short short4v;
typedef __attribute__((ext_vector_type(4))) float float4v;

__device__ __forceinline__ short f2b(float f) {
    __hip_bfloat16 h = __float2bfloat16(f);
    return __builtin_bit_cast(short, h);
}
__device__ __forceinline__ float b2f(short s) {
    unsigned u = ((unsigned)(unsigned short)s) << 16;
    return __builtin_bit_cast(float, u);
}

// ---------------------------------------------------------------------------
// x (fp32) -> xb (bf16), n4 = elems/4
// ---------------------------------------------------------------------------
__global__ __launch_bounds__(256) void convert_x_kernel(
    const float* __restrict__ src, short* __restrict__ dst, int n4)
{
    int id = blockIdx.x * 256 + threadIdx.x;
    if (id >= n4) return;
    float4 v = reinterpret_cast<const float4*>(src)[id];
    short4v o;
    o[0] = f2b(v.x); o[1] = f2b(v.y); o[2] = f2b(v.z); o[3] = f2b(v.w);
    reinterpret_cast<short4v*>(dst)[id] = o;
}

// ---------------------------------------------------------------------------
// [Wq|Wk] -> transposed bf16 Wt[576][2048]. grid (9 n-tiles, 32 k-tiles)
// ---------------------------------------------------------------------------
__global__ __launch_bounds__(256) void convert_w_kernel(
    const float* __restrict__ Wq, const float* __restrict__ Wk,
    short* __restrict__ Wt)
{
    const int n0 = blockIdx.x * 64;
    const int k0 = blockIdx.y * 64;
    const int tid = threadIdx.x;
    __shared__ float ts[64][65];
    for (int i = tid; i < 4096; i += 256) {
        int kk = i >> 6, nn = i & 63;
        int n = n0 + nn, k = k0 + kk;
        float v = (n < 512) ? Wq[(long)k * 512 + n] : Wk[(long)k * 64 + (n - 512)];
        ts[kk][nn] = v;
    }
    __syncthreads();
    for (int i = tid; i < 4096; i += 256) {
        int nn = i >> 6, kk = i & 63;
        Wt[(long)(n0 + nn) * 2048 + k0 + kk] = f2b(ts[kk][nn]);
    }
}

// ---------------------------------------------------------------------------
// qk[row][n] = bias (bq|bk), row-per-block. Split-K GEMM accumulates on top.
// ---------------------------------------------------------------------------
__global__ __launch_bounds__(256) void bias_init_kernel(
    const float* __restrict__ bq, const float* __restrict__ bk,
    float* __restrict__ qk)
{
    const int row = blockIdx.x;
    for (int n = threadIdx.x; n < 576; n += 256)
        qk[(long)row * 576 + n] = (n < 512) ? bq[n] : bk[n - 512];
}

// ---------------------------------------------------------------------------
// qk projection, split-K=2: qk[2048][576] += xb[2048][2048] @ Wt[576][2048]^T
// 64x64 tile, 4 waves 2x2, 16x16x32 bf16 MFMA, fp32 atomicAdd epilogue.
// grid (9, 32, 2)
// ---------------------------------------------------------------------------
__global__ __launch_bounds__(256) void qkproj_kernel(
    const short* __restrict__ xb, const short* __restrict__ Wt,
    float* __restrict__ qk)
{
    __shared__ short As[64][72];
    __shared__ short Bs[64][72];

    const int tid = threadIdx.x;
    const int wave = tid >> 6;
    const int lane = tid & 63;
    const int wm = wave >> 1, wn = wave & 1;
    const int m15 = lane & 15;
    const int quad = lane >> 4;
    const int row0 = blockIdx.y * 64;
    const int col0 = blockIdx.x * 64;
    const int kbase = blockIdx.z * 1024;

    float4v acc[2][2];
    #pragma unroll
    for (int i = 0; i < 2; ++i)
        #pragma unroll
        for (int j = 0; j < 2; ++j)
            #pragma unroll
            for (int r = 0; r < 4; ++r) acc[i][j][r] = 0.f;

    for (int kt = 0; kt < 16; ++kt) {
        int k0 = kbase + kt * 64;
        #pragma unroll
        for (int p = 0; p < 2; ++p) {
            int i = tid + p * 256;
            int m = i >> 3, kq = i & 7;
            *reinterpret_cast<short8*>(&As[m][kq * 8]) =
                *reinterpret_cast<const short8*>(&xb[(long)(row0 + m) * 2048 + k0 + kq * 8]);
        }
        #pragma unroll
        for (int p = 0; p < 2; ++p) {
            int i = tid + p * 256;
            int n = i >> 3, kq = i & 7;
            *reinterpret_cast<short8*>(&Bs[n][kq * 8]) =
                *reinterpret_cast<const short8*>(&Wt[(long)(col0 + n) * 2048 + k0 + kq * 8]);
        }
        __syncthreads();
        #pragma unroll
        for (int ks = 0; ks < 2; ++ks) {
            short8 a[2], b[2];
            #pragma unroll
            for (int t = 0; t < 2; ++t) {
                a[t] = *reinterpret_cast<const short8*>(&As[wm * 32 + t * 16 + m15][ks * 32 + quad * 8]);
                b[t] = *reinterpret_cast<const short8*>(&Bs[wn * 32 + t * 16 + m15][ks * 32 + quad * 8]);
            }
            #pragma unroll
            for (int ti = 0; ti < 2; ++ti)
                #pragma unroll
                for (int tj = 0; tj < 2; ++tj)
                    acc[ti][tj] = __builtin_amdgcn_mfma_f32_16x16x32_bf16(
                        a[ti], b[tj], acc[ti][tj], 0, 0, 0);
        }
        __syncthreads();
    }

    #pragma unroll
    for (int ti = 0; ti < 2; ++ti)
        #pragma unroll
        for (int r = 0; r < 4; ++r) {
            int row = row0 + wm * 32 + ti * 16 + quad * 4 + r;
            #pragma unroll
            for (int tj = 0; tj < 2; ++tj) {
                int col = col0 + wn * 32 + tj * 16 + m15;
                atomicAdd(&qk[(long)row * 576 + col], acc[ti][tj][r]);
            }
        }
}

// ---------------------------------------------------------------------------
// qk fp32 -> qkb bf16 (1,179,648 elems). grid 1152.
// ---------------------------------------------------------------------------
__global__ __launch_bounds__(256) void convert_qk_kernel(
    const float* __restrict__ qk, short* __restrict__ qkb)
{
    int id = blockIdx.x * 256 + threadIdx.x;   // < 294912
    float4 v = reinterpret_cast<const float4*>(qk)[id];
    short4v o;
    o[0] = f2b(v.x); o[1] = f2b(v.y); o[2] = f2b(v.z); o[3] = f2b(v.w);
    reinterpret_cast<short4v*>(qkb)[id] = o;
}

// ---------------------------------------------------------------------------
// QK^T via MFMA, all 8 heads, bf16 in. S[h,l,s] bf16.
// grid (16 s-tiles, 16 l-tiles, 2 b); S is per-batch (b in ptr arg is batch 0
// base, batch handled by z and Sb stride)
// ---------------------------------------------------------------------------
__global__ __launch_bounds__(256) void qk_s_kernel(
    const short* __restrict__ qkb, short* __restrict__ S)
{
    const int s0 = blockIdx.x * 64;
    const int l0 = blockIdx.y * 64;
    const int b = blockIdx.z;
    const int tid = threadIdx.x;
    short* Sz = S + ((long)b << 23);   // 8*1024*1024 per batch

    __shared__ short Qs[64][520];   // 64 l x 512 d (+8 pad)
    __shared__ short Ks[64][72];    // 64 s x 64 d  (+8 pad)

    #pragma unroll
    for (int p = 0; p < 16; ++p) {
        int i = tid + p * 256;
        int row = i >> 6, d8 = i & 63;
        *reinterpret_cast<short8*>(&Qs[row][d8 * 8]) =
            *reinterpret_cast<const short8*>(&qkb[(long)((b << 10) + l0 + row) * 576 + d8 * 8]);
    }
    #pragma unroll
    for (int p = 0; p < 2; ++p) {
        int i = tid + p * 256;
        int row = i >> 3, d8 = i & 7;
        *reinterpret_cast<short8*>(&Ks[row][d8 * 8]) =
            *reinterpret_cast<const short8*>(&qkb[(long)((b << 10) + s0 + row) * 576 + 512 + d8 * 8]);
    }
    __syncthreads();

    const int wave = tid >> 6;
    const int lane = tid & 63;
    const int wm = wave >> 1, wn = wave & 1;
    const int m15 = lane & 15;
    const int quad = lane >> 4;

    for (int h = 0; h < 8; ++h) {
        float4v acc[2][2];
        #pragma unroll
        for (int i = 0; i < 2; ++i)
            #pragma unroll
            for (int j = 0; j < 2; ++j)
                #pragma unroll
                for (int r = 0; r < 4; ++r) acc[i][j][r] = 0.f;

        #pragma unroll
        for (int ks = 0; ks < 2; ++ks) {
            short8 a[2], bfr[2];
            #pragma unroll
            for (int t = 0; t < 2; ++t) {
                a[t]   = *reinterpret_cast<const short8*>(
                    &Qs[wm * 32 + t * 16 + m15][h * 64 + ks * 32 + quad * 8]);
                bfr[t] = *reinterpret_cast<const short8*>(
                    &Ks[wn * 32 + t * 16 + m15][ks * 32 + quad * 8]);
            }
            #pragma unroll
            for (int ti = 0; ti < 2; ++ti)
                #pragma unroll
                for (int tj = 0; tj < 2; ++tj)
                    acc[ti][tj] = __builtin_amdgcn_mfma_f32_16x16x32_bf16(
                        a[ti], bfr[tj], acc[ti][tj], 0, 0, 0);
        }

        #pragma unroll
        for (int ti = 0; ti < 2; ++ti)
            #pragma unroll
            for (int r = 0; r < 4; ++r) {
                int l = l0 + wm * 32 + ti * 16 + quad * 4 + r;
                #pragma unroll
                for (int tj = 0; tj < 2; ++tj) {
                    int s = s0 + wn * 32 + tj * 16 + m15;
                    Sz[((long)h << 20) + (l << 10) + s] = f2b(acc[ti][tj][r] * 0.125f);
                }
            }
    }
}

// ---------------------------------------------------------------------------
// Softmax over s for 8 heads + head-average -> P bf16 [b][l][s].
// grid (1024, 2). Thread (h=tid>>5, j=tid&31) owns s = i*32+j.
// ---------------------------------------------------------------------------
__global__ __launch_bounds__(256) void softmax_avg_kernel(
    const short* __restrict__ S, short* __restrict__ P)
{
    const int l = blockIdx.x;
    const int b = blockIdx.y;
    const int tid = threadIdx.x;
    const int h = tid >> 5, j = tid & 31;
    const short* Sz = S + ((long)b << 23);

    __shared__ float es[8][1032];
    __shared__ float invd[8];

    const short* row = &Sz[((long)h << 20) + (l << 10)];
    float vals[32];
    float pm = -1e30f;
    #pragma unroll
    for (int i = 0; i < 32; ++i) {
        float f = b2f(row[i * 32 + j]);
        vals[i] = f;
        pm = fmaxf(pm, f);
    }
    #pragma unroll
    for (int off = 16; off > 0; off >>= 1) pm = fmaxf(pm, __shfl_down(pm, off, 32));
    pm = __shfl(pm, 0, 32);

    float ps = 0.f;
    #pragma unroll
    for (int i = 0; i < 32; ++i) {
        float e = __expf(vals[i] - pm);
        vals[i] = e;
        ps += e;
    }
    #pragma unroll
    for (int off = 16; off > 0; off >>= 1) ps += __shfl_down(ps, off, 32);
    if (j == 0) invd[h] = 1.f / (8.f * ps);
    __syncthreads();

    const float w = invd[h];
    #pragma unroll
    for (int i = 0; i < 32; ++i) es[h][i * 32 + j] = vals[i] * w;
    __syncthreads();

    for (int s = tid; s < 1024; s += 256) {
        float p = 0.f;
        #pragma unroll
        for (int hh = 0; hh < 8; ++hh) p += es[hh][s];
        P[((long)b << 20) + (l << 10) + s] = f2b(p);
    }
}

// ---------------------------------------------------------------------------
// Per-channel value projection -> TRANSPOSED bf16 vt[b][c*32+o][l]
// ---------------------------------------------------------------------------
__global__ __launch_bounds__(256) void vproj_kernel(
    const float* __restrict__ x, const float* __restrict__ Wv,
    const float* __restrict__ bv, short* __restrict__ vt)
{
    const int c = blockIdx.x;
    const int chunk = blockIdx.y;       // 0..31
    const int b = chunk >> 4;
    const int l0 = (chunk & 15) * 64;
    const int tid = threadIdx.x;
    __shared__ float Wc[32][33];
    __shared__ float xs[64][33];
    for (int i = tid; i < 1024; i += 256)
        Wc[i >> 5][i & 31] = Wv[(c * 32 + (i >> 5)) * 32 + (i & 31)];
    for (int i = tid; i < 2048; i += 256) {
        int s = i >> 5, r = i & 31;
        xs[s][r] = x[((long)(b << 10) + l0 + s) * 2048 + c * 32 + r];
    }
    __syncthreads();
    const int s = tid & 63;
    const int og = tid >> 6;
    #pragma unroll
    for (int oi = 0; oi < 8; ++oi) {
        int o = og * 8 + oi;
        float acc = bv[c * 32 + o];
        #pragma unroll
        for (int r = 0; r < 32; ++r) acc += xs[s][r] * Wc[r][o];
        vt[(long)b * (2048 * 1024) + (long)(c * 32 + o) * 1024 + l0 + s] = f2b(acc);
    }
}

// ---------------------------------------------------------------------------
// Sink: softmax over l of sink_q.k, atomicAdd (1/32)*attn into Psink[b][l].
// grid 64 = (b, h*4+si)
// ---------------------------------------------------------------------------
__global__ __launch_bounds__(256) void sink_kernel(
    const float* __restrict__ sink_q, const short* __restrict__ qkb,
    float* __restrict__ Psink)
{
    const int z = blockIdx.x;
    const int b = z >> 5;
    const int idx = z & 31;
    const int tid = threadIdx.x;

    __shared__ float sq[64];
    __shared__ float lgl[1024];
    __shared__ float red[4];
    __shared__ float mxs, invs;

    if (tid < 64) sq[tid] = sink_q[idx * 64 + tid];
    __syncthreads();

    float lmax = -1e30f;
    for (int l = tid; l < 1024; l += 256) {
        const short* kp = &qkb[(long)((b << 10) + l) * 576 + 512];
        float acc = 0.f;
        #pragma unroll
        for (int d8 = 0; d8 < 8; ++d8) {
            short8 kv = *reinterpret_cast<const short8*>(&kp[d8 * 8]);
            #pragma unroll
            for (int j = 0; j < 8; ++j) acc += b2f(kv[j]) * sq[d8 * 8 + j];
        }
        acc *= 0.125f;
        lgl[l] = acc;
        lmax = fmaxf(lmax, acc);
    }
    #pragma unroll
    for (int off = 32; off > 0; off >>= 1) lmax = fmaxf(lmax, __shfl_down(lmax, off, 64));
    if ((tid & 63) == 0) red[tid >> 6] = lmax;
    __syncthreads();
    if (tid == 0) mxs = fmaxf(fmaxf(red[0], red[1]), fmaxf(red[2], red[3]));
    __syncthreads();

    const float m = mxs;
    float psum = 0.f;
    for (int l = tid; l < 1024; l += 256) {
        float e = __expf(lgl[l] - m);
        lgl[l] = e;
        psum += e;
    }
    #pragma unroll
    for (int off = 32; off > 0; off >>= 1) psum += __shfl_down(psum, off, 64);
    if ((tid & 63) == 0) red[tid >> 6] = psum;
    __syncthreads();
    if (tid == 0) invs = 1.f / (red[0] + red[1] + red[2] + red[3]);
    __syncthreads();

    const float wgt = invs * (1.f / 32.f);
    for (int l = tid; l < 1024; l += 256)
        atomicAdd(&Psink[(b << 10) + l], lgl[l] * wgt);
}

// ---------------------------------------------------------------------------
// Ysink[b][co] = sum_l Psink[b][l] * vt[b][co][l]. grid (512, 2), wave per co.
// ---------------------------------------------------------------------------
__global__ __launch_bounds__(256) void sinky_kernel(
    const float* __restrict__ Psink, const short* __restrict__ vt,
    float* __restrict__ Ysink)
{
    const int b = blockIdx.y;
    const int tid = threadIdx.x;
    __shared__ float ps[1024];
    {
        float4 v = reinterpret_cast<const float4*>(&Psink[b << 10])[tid];
        *reinterpret_cast<float4*>(&ps[tid * 4]) = v;
    }
    __syncthreads();
    const int wave = tid >> 6;
    const int lane = tid & 63;
    const int co = blockIdx.x * 4 + wave;
    const short* vp = &vt[((long)b * 2048 + co) * 1024];
    float acc = 0.f;
    #pragma unroll
    for (int t = 0; t < 16; ++t) {
        int l = t * 64 + lane;
        acc += ps[l] * b2f(vp[l]);
    }
    #pragma unroll
    for (int off = 32; off > 0; off >>= 1) acc += __shfl_down(acc, off, 64);
    if (lane == 0) Ysink[(b << 11) + co] = acc;
}

// ---------------------------------------------------------------------------
// Fused Y-GEMM + MFMA output projection:
//  Ytile[64l x 64co] = P[b] @ vt[b]^T        (bf16 MFMA, K=1024)
//  out[64l x 64cr]   = x + bo + (Yt+Ysink) @ blockdiag(Wo)  (2nd MFMA pass)
// grid (32 co-tiles, 16 l-tiles, 2 b)
// ---------------------------------------------------------------------------
__global__ __launch_bounds__(256) void y_fused_kernel(
    const short* __restrict__ P, const short* __restrict__ vt,
    const float* __restrict__ Ysink, const float* __restrict__ Wo,
    const float* __restrict__ bo, const float* __restrict__ x,
    float* __restrict__ out)
{
    __shared__ short As[64][72];
    __shared__ short Bs[64][72];

    const int tid = threadIdx.x;
    const int b = blockIdx.z;
    const int col0 = blockIdx.x * 64;
    const int row0 = blockIdx.y * 64;
    const short* Pz = P + ((long)b << 20);
    const short* Vz = vt + ((long)b * 2048 * 1024);

    const int wave = tid >> 6;
    const int lane = tid & 63;
    const int wm = wave >> 1, wn = wave & 1;
    const int m15 = lane & 15;
    const int quad = lane >> 4;

    float4v acc[2][2];
    #pragma unroll
    for (int i = 0; i < 2; ++i)
        #pragma unroll
        for (int j = 0; j < 2; ++j)
            #pragma unroll
            for (int r = 0; r < 4; ++r) acc[i][j][r] = 0.f;

    for (int kt = 0; kt < 16; ++kt) {
        int k0 = kt * 64;
        #pragma unroll
        for (int p = 0; p < 2; ++p) {
            int i = tid + p * 256;
            int m = i >> 3, kq = i & 7;
            *reinterpret_cast<short8*>(&As[m][kq * 8]) =
                *reinterpret_cast<const short8*>(&Pz[(long)(row0 + m) * 1024 + k0 + kq * 8]);
        }
        #pragma unroll
        for (int p = 0; p < 2; ++p) {
            int i = tid + p * 256;
            int n = i >> 3, kq = i & 7;
            *reinterpret_cast<short8*>(&Bs[n][kq * 8]) =
                *reinterpret_cast<const short8*>(&Vz[(long)(col0 + n) * 1024 + k0 + kq * 8]);
        }
        __syncthreads();
        #pragma unroll
        for (int ks = 0; ks < 2; ++ks) {
            short8 a[2], bb[2];
            #pragma unroll
            for (int t = 0; t < 2; ++t) {
                a[t]  = *reinterpret_cast<const short8*>(&As[wm * 32 + t * 16 + m15][ks * 32 + quad * 8]);
                bb[t] = *reinterpret_cast<const short8*>(&Bs[wn * 32 + t * 16 + m15][ks * 32 + quad * 8]);
            }
            #pragma unroll
            for (int ti = 0; ti < 2; ++ti)
                #pragma unroll
                for (int tj = 0; tj < 2; ++tj)
                    acc[ti][tj] = __builtin_amdgcn_mfma_f32_16x16x32_bf16(
                        a[ti], bb[tj], acc[ti][tj], 0, 0, 0);
        }
        __syncthreads();
    }

    // ---- epilogue pass 2: out = x + bo + (Yt + Ysink) @ blockdiag(Wo) ----
    // Yt (bf16, A-layout source) -> As[l][co]; WoB (bf16, B-layout) -> Bs[n][k]
    float ysv[2];
    #pragma unroll
    for (int tj = 0; tj < 2; ++tj)
        ysv[tj] = Ysink[(b << 11) + col0 + wn * 32 + tj * 16 + m15];

    #pragma unroll
    for (int ti = 0; ti < 2; ++ti)
        #pragma unroll
        for (int r = 0; r < 4; ++r) {
            int row = wm * 32 + ti * 16 + quad * 4 + r;
            #pragma unroll
            for (int tj = 0; tj < 2; ++tj) {
                int col = wn * 32 + tj * 16 + m15;
                As[row][col] = f2b(acc[ti][tj][r] + ysv[tj]);
            }
        }
    // WoB[n][k] = (same channel) ? Wo[c0 + n/32][o=k&31][r=n&31] : 0
    const int c0 = col0 >> 5;
    for (int i = tid; i < 4096; i += 256) {
        int n = i >> 6, k = i & 63;
        short v = 0;
        if ((n >> 5) == (k >> 5))
            v = f2b(Wo[((long)(c0 + (n >> 5)) * 32 + (k & 31)) * 32 + (n & 31)]);
        Bs[n][k] = v;
    }
    __syncthreads();

    float4v acc2[2][2];
    #pragma unroll
    for (int i = 0; i < 2; ++i)
        #pragma unroll
        for (int j = 0; j < 2; ++j)
            #pragma unroll
            for (int r = 0; r < 4; ++r) acc2[i][j][r] = 0.f;

    #pragma unroll
    for (int ks = 0; ks < 2; ++ks) {
        short8 a[2], bb[2];
        #pragma unroll
        for (int t = 0; t < 2; ++t) {
            a[t]  = *reinterpret_cast<const short8*>(&As[wm * 32 + t * 16 + m15][ks * 32 + quad * 8]);
            bb[t] = *reinterpret_cast<const short8*>(&Bs[wn * 32 + t * 16 + m15][ks * 32 + quad * 8]);
        }
        #pragma unroll
        for (int ti = 0; ti < 2; ++ti)
            #pragma unroll
            for (int tj = 0; tj < 2; ++tj)
                acc2[ti][tj] = __builtin_amdgcn_mfma_f32_16x16x32_bf16(
                    a[ti], bb[tj], acc2[ti][tj], 0, 0, 0);
    }

    float bov[2];
    #pragma unroll
    for (int tj = 0; tj < 2; ++tj)
        bov[tj] = bo[col0 + wn * 32 + tj * 16 + m15];

    #pragma unroll
    for (int ti = 0; ti < 2; ++ti)
        #pragma unroll
        for (int r = 0; r < 4; ++r) {
            int row = (b << 10) + row0 + wm * 32 + ti * 16 + quad * 4 + r;
            #pragma unroll
            for (int tj = 0; tj < 2; ++tj) {
                int col = col0 + wn * 32 + tj * 16 + m15;
                long oi = (long)row * 2048 + col;
                out[oi] = x[oi] + bov[tj] + acc2[ti][tj][r];
            }
        }
}

// ---------------------------------------------------------------------------
extern "C" void kernel_launch(void* const* d_in, const int* in_sizes, int n_in,
                              void* d_out, int out_size, void* d_ws, size_t ws_size,
                              hipStream_t stream)
{
    const float* x  = (const float*)d_in[0];
    const float* Wq = (const float*)d_in[1];
    const float* bq = (const float*)d_in[2];
    const float* Wk = (const float*)d_in[3];
    const float* bk = (const float*)d_in[4];
    const float* Wv = (const float*)d_in[5];
    const float* bv = (const float*)d_in[6];
    const float* Wo = (const float*)d_in[7];
    const float* bo = (const float*)d_in[8];
    const float* sq = (const float*)d_in[9];
    float* out = (float*)d_out;

    // workspace layout (float units)
    float* ws = (float*)d_ws;
    float* qk     = ws;                          // 1,179,648 f (2048x576 fp32)
    short* qkb    = (short*)(ws + 1179648);      //   589,824 f (bf16)
    short* P      = (short*)(ws + 1769472);      // 1,048,576 f (2x1024x1024 bf16)
    float* Psink  = ws + 2818048;                //     2,048 f
    short* vt     = (short*)(ws + 2820096);      // 2,097,152 f (bf16)
    float* Ysink  = ws + 4917248;                //     4,096 f
    float* region = ws + 4921344;                // 8,388,608 f shared: {xb,Wt} -> S
    short* xb     = (short*)region;              // 2,097,152 f (bf16)
    short* Wt     = (short*)(region + 2097152);  //   589,824 f (bf16)
    short* Sb     = (short*)region;              // 2 x 8x1024x1024 bf16 = 8,388,608 f

    dim3 blk(256);

    convert_x_kernel<<<dim3(1024 * 1024 / 256), blk, 0, stream>>>(x, xb, 1048576);
    convert_w_kernel<<<dim3(9, 32), blk, 0, stream>>>(Wq, Wk, Wt);
    bias_init_kernel<<<dim3(2048), blk, 0, stream>>>(bq, bk, qk);
    qkproj_kernel<<<dim3(9, 32, 2), blk, 0, stream>>>(xb, Wt, qk);
    convert_qk_kernel<<<dim3(1152), blk, 0, stream>>>(qk, qkb);
    vproj_kernel<<<dim3(64, 32), blk, 0, stream>>>(x, Wv, bv, vt);
    qk_s_kernel<<<dim3(16, 16, 2), blk, 0, stream>>>(qkb, Sb);
    softmax_avg_kernel<<<dim3(1024, 2), blk, 0, stream>>>(Sb, P);
    hipMemsetAsync(Psink, 0, 2048 * sizeof(float), stream);
    sink_kernel<<<dim3(64), blk, 0, stream>>>(sq, qkb, Psink);
    sinky_kernel<<<dim3(512, 2), blk, 0, stream>>>(Psink, vt, Ysink);
    y_fused_kernel<<<dim3(32, 16, 2), blk, 0, stream>>>(
        P, vt, Ysink, Wo, bo, x, out);
}

// Round 6
// 194.247 us; speedup vs baseline: 5.7271x; 1.0691x over previous
//
#include <hip/hip_runtime.h>
#include <hip/hip_bf16.h>
#include <math.h>

// B=2, L=1024, C=64, R=32, RV=32, DQK=64, H=8, NSINK=4
// x: (2,1024,64,32) fp32; out same. BL = 2048.

typedef __attribute__((ext_vector_type(8))) short short8;
typedef __attribute__((ext_vector_type(4))) short short4v;
typedef __attribute__((ext_vector_type(4))) float float4v;

__device__ __forceinline__ short f2b(float f) {
    __hip_bfloat16 h = __float2bfloat16(f);
    return __builtin_bit_cast(short, h);
}
__device__ __forceinline__ float b2f(short s) {
    unsigned u = ((unsigned)(unsigned short)s) << 16;
    return __builtin_bit_cast(float, u);
}

// ---------------------------------------------------------------------------
// [Wq|Wk] -> transposed bf16 Wt[576][2048]. grid (9 n-tiles, 32 k-tiles)
// ---------------------------------------------------------------------------
__global__ __launch_bounds__(256) void convert_w_kernel(
    const float* __restrict__ Wq, const float* __restrict__ Wk,
    short* __restrict__ Wt)
{
    const int n0 = blockIdx.x * 64;
    const int k0 = blockIdx.y * 64;
    const int tid = threadIdx.x;
    __shared__ float ts[64][65];
    for (int i = tid; i < 4096; i += 256) {
        int kk = i >> 6, nn = i & 63;
        int n = n0 + nn, k = k0 + kk;
        float v = (n < 512) ? Wq[(long)k * 512 + n] : Wk[(long)k * 64 + (n - 512)];
        ts[kk][nn] = v;
    }
    __syncthreads();
    for (int i = tid; i < 4096; i += 256) {
        int nn = i >> 6, kk = i & 63;
        Wt[(long)(n0 + nn) * 2048 + k0 + kk] = f2b(ts[kk][nn]);
    }
}

// ---------------------------------------------------------------------------
// Per-channel value projection -> TRANSPOSED bf16 vt[b][c*32+o][l].
// Also emits xb (bf16 copy of x) since it touches every x element once.
// grid (C=64, 32 chunks of 64 l)
// ---------------------------------------------------------------------------
__global__ __launch_bounds__(256) void vproj_kernel(
    const float* __restrict__ x, const float* __restrict__ Wv,
    const float* __restrict__ bv, short* __restrict__ vt,
    short* __restrict__ xb)
{
    const int c = blockIdx.x;
    const int chunk = blockIdx.y;       // 0..31
    const int b = chunk >> 4;
    const int l0 = (chunk & 15) * 64;
    const int tid = threadIdx.x;
    __shared__ float Wc[32][33];
    __shared__ float xs[64][33];
    for (int i = tid; i < 1024; i += 256)
        Wc[i >> 5][i & 31] = Wv[(c * 32 + (i >> 5)) * 32 + (i & 31)];
    for (int i = tid; i < 2048; i += 256) {
        int s = i >> 5, r = i & 31;
        long gi = ((long)(b << 10) + l0 + s) * 2048 + c * 32 + r;
        float v = x[gi];
        xs[s][r] = v;
        xb[gi] = f2b(v);
    }
    __syncthreads();
    const int s = tid & 63;
    const int og = tid >> 6;
    #pragma unroll
    for (int oi = 0; oi < 8; ++oi) {
        int o = og * 8 + oi;
        float acc = bv[c * 32 + o];
        #pragma unroll
        for (int r = 0; r < 32; ++r) acc += xs[s][r] * Wc[r][o];
        vt[(long)b * (2048 * 1024) + (long)(c * 32 + o) * 1024 + l0 + s] = f2b(acc);
    }
}

// ---------------------------------------------------------------------------
// qk projection, split-K=2, NO atomics: qkpart[z][2048][576] = partial GEMM.
// 64x64 tile, 4 waves 2x2, 16x16x32 bf16 MFMA. grid (9, 32, 2)
// ---------------------------------------------------------------------------
__global__ __launch_bounds__(256) void qkproj_kernel(
    const short* __restrict__ xb, const short* __restrict__ Wt,
    float* __restrict__ qkpart)
{
    __shared__ short As[64][72];
    __shared__ short Bs[64][72];

    const int tid = threadIdx.x;
    const int wave = tid >> 6;
    const int lane = tid & 63;
    const int wm = wave >> 1, wn = wave & 1;
    const int m15 = lane & 15;
    const int quad = lane >> 4;
    const int row0 = blockIdx.y * 64;
    const int col0 = blockIdx.x * 64;
    const int kbase = blockIdx.z * 1024;
    float* outz = qkpart + (long)blockIdx.z * 1179648;

    float4v acc[2][2];
    #pragma unroll
    for (int i = 0; i < 2; ++i)
        #pragma unroll
        for (int j = 0; j < 2; ++j)
            #pragma unroll
            for (int r = 0; r < 4; ++r) acc[i][j][r] = 0.f;

    for (int kt = 0; kt < 16; ++kt) {
        int k0 = kbase + kt * 64;
        #pragma unroll
        for (int p = 0; p < 2; ++p) {
            int i = tid + p * 256;
            int m = i >> 3, kq = i & 7;
            *reinterpret_cast<short8*>(&As[m][kq * 8]) =
                *reinterpret_cast<const short8*>(&xb[(long)(row0 + m) * 2048 + k0 + kq * 8]);
        }
        #pragma unroll
        for (int p = 0; p < 2; ++p) {
            int i = tid + p * 256;
            int n = i >> 3, kq = i & 7;
            *reinterpret_cast<short8*>(&Bs[n][kq * 8]) =
                *reinterpret_cast<const short8*>(&Wt[(long)(col0 + n) * 2048 + k0 + kq * 8]);
        }
        __syncthreads();
        #pragma unroll
        for (int ks = 0; ks < 2; ++ks) {
            short8 a[2], b[2];
            #pragma unroll
            for (int t = 0; t < 2; ++t) {
                a[t] = *reinterpret_cast<const short8*>(&As[wm * 32 + t * 16 + m15][ks * 32 + quad * 8]);
                b[t] = *reinterpret_cast<const short8*>(&Bs[wn * 32 + t * 16 + m15][ks * 32 + quad * 8]);
            }
            #pragma unroll
            for (int ti = 0; ti < 2; ++ti)
                #pragma unroll
                for (int tj = 0; tj < 2; ++tj)
                    acc[ti][tj] = __builtin_amdgcn_mfma_f32_16x16x32_bf16(
                        a[ti], b[tj], acc[ti][tj], 0, 0, 0);
        }
        __syncthreads();
    }

    #pragma unroll
    for (int ti = 0; ti < 2; ++ti)
        #pragma unroll
        for (int r = 0; r < 4; ++r) {
            int row = row0 + wm * 32 + ti * 16 + quad * 4 + r;
            #pragma unroll
            for (int tj = 0; tj < 2; ++tj) {
                int col = col0 + wn * 32 + tj * 16 + m15;
                outz[(long)row * 576 + col] = acc[ti][tj][r];
            }
        }
}

// ---------------------------------------------------------------------------
// qkb = bf16( qkpart[0] + qkpart[1] + bias(bq|bk) ). grid 1152, float4/thread.
// ---------------------------------------------------------------------------
__global__ __launch_bounds__(256) void convert_qk_kernel(
    const float* __restrict__ qkpart, const float* __restrict__ bq,
    const float* __restrict__ bk, short* __restrict__ qkb)
{
    int id = blockIdx.x * 256 + threadIdx.x;   // < 294912
    float4 a = reinterpret_cast<const float4*>(qkpart)[id];
    float4 b = reinterpret_cast<const float4*>(qkpart + 1179648)[id];
    int col4 = (id % 144) * 4;
    float4 bias = (col4 < 512)
        ? *reinterpret_cast<const float4*>(&bq[col4])
        : *reinterpret_cast<const float4*>(&bk[col4 - 512]);
    short4v o;
    o[0] = f2b(a.x + b.x + bias.x);
    o[1] = f2b(a.y + b.y + bias.y);
    o[2] = f2b(a.z + b.z + bias.z);
    o[3] = f2b(a.w + b.w + bias.w);
    reinterpret_cast<short4v*>(qkb)[id] = o;
}

// ---------------------------------------------------------------------------
// QK^T via MFMA, all 8 heads, bf16 in. S[h,l,s] bf16. grid (16, 16, 2)
// ---------------------------------------------------------------------------
__global__ __launch_bounds__(256) void qk_s_kernel(
    const short* __restrict__ qkb, short* __restrict__ S)
{
    const int s0 = blockIdx.x * 64;
    const int l0 = blockIdx.y * 64;
    const int b = blockIdx.z;
    const int tid = threadIdx.x;
    short* Sz = S + ((long)b << 23);   // 8*1024*1024 per batch

    __shared__ short Qs[64][520];   // 64 l x 512 d (+8 pad)
    __shared__ short Ks[64][72];    // 64 s x 64 d  (+8 pad)

    #pragma unroll
    for (int p = 0; p < 16; ++p) {
        int i = tid + p * 256;
        int row = i >> 6, d8 = i & 63;
        *reinterpret_cast<short8*>(&Qs[row][d8 * 8]) =
            *reinterpret_cast<const short8*>(&qkb[(long)((b << 10) + l0 + row) * 576 + d8 * 8]);
    }
    #pragma unroll
    for (int p = 0; p < 2; ++p) {
        int i = tid + p * 256;
        int row = i >> 3, d8 = i & 7;
        *reinterpret_cast<short8*>(&Ks[row][d8 * 8]) =
            *reinterpret_cast<const short8*>(&qkb[(long)((b << 10) + s0 + row) * 576 + 512 + d8 * 8]);
    }
    __syncthreads();

    const int wave = tid >> 6;
    const int lane = tid & 63;
    const int wm = wave >> 1, wn = wave & 1;
    const int m15 = lane & 15;
    const int quad = lane >> 4;

    for (int h = 0; h < 8; ++h) {
        float4v acc[2][2];
        #pragma unroll
        for (int i = 0; i < 2; ++i)
            #pragma unroll
            for (int j = 0; j < 2; ++j)
                #pragma unroll
                for (int r = 0; r < 4; ++r) acc[i][j][r] = 0.f;

        #pragma unroll
        for (int ks = 0; ks < 2; ++ks) {
            short8 a[2], bfr[2];
            #pragma unroll
            for (int t = 0; t < 2; ++t) {
                a[t]   = *reinterpret_cast<const short8*>(
                    &Qs[wm * 32 + t * 16 + m15][h * 64 + ks * 32 + quad * 8]);
                bfr[t] = *reinterpret_cast<const short8*>(
                    &Ks[wn * 32 + t * 16 + m15][ks * 32 + quad * 8]);
            }
            #pragma unroll
            for (int ti = 0; ti < 2; ++ti)
                #pragma unroll
                for (int tj = 0; tj < 2; ++tj)
                    acc[ti][tj] = __builtin_amdgcn_mfma_f32_16x16x32_bf16(
                        a[ti], bfr[tj], acc[ti][tj], 0, 0, 0);
        }

        #pragma unroll
        for (int ti = 0; ti < 2; ++ti)
            #pragma unroll
            for (int r = 0; r < 4; ++r) {
                int l = l0 + wm * 32 + ti * 16 + quad * 4 + r;
                #pragma unroll
                for (int tj = 0; tj < 2; ++tj) {
                    int s = s0 + wn * 32 + tj * 16 + m15;
                    Sz[((long)h << 20) + (l << 10) + s] = f2b(acc[ti][tj][r] * 0.125f);
                }
            }
    }
}

// ---------------------------------------------------------------------------
// Softmax over s for 8 heads + head-average -> P bf16 [b][l][s]. grid (1024,2)
// ---------------------------------------------------------------------------
__global__ __launch_bounds__(256) void softmax_avg_kernel(
    const short* __restrict__ S, short* __restrict__ P)
{
    const int l = blockIdx.x;
    const int b = blockIdx.y;
    const int tid = threadIdx.x;
    const int h = tid >> 5, j = tid & 31;
    const short* Sz = S + ((long)b << 23);

    __shared__ float es[8][1032];
    __shared__ float invd[8];

    const short* row = &Sz[((long)h << 20) + (l << 10)];
    float vals[32];
    float pm = -1e30f;
    #pragma unroll
    for (int i = 0; i < 32; ++i) {
        float f = b2f(row[i * 32 + j]);
        vals[i] = f;
        pm = fmaxf(pm, f);
    }
    #pragma unroll
    for (int off = 16; off > 0; off >>= 1) pm = fmaxf(pm, __shfl_down(pm, off, 32));
    pm = __shfl(pm, 0, 32);

    float ps = 0.f;
    #pragma unroll
    for (int i = 0; i < 32; ++i) {
        float e = __expf(vals[i] - pm);
        vals[i] = e;
        ps += e;
    }
    #pragma unroll
    for (int off = 16; off > 0; off >>= 1) ps += __shfl_down(ps, off, 32);
    if (j == 0) invd[h] = 1.f / (8.f * ps);
    __syncthreads();

    const float w = invd[h];
    #pragma unroll
    for (int i = 0; i < 32; ++i) es[h][i * 32 + j] = vals[i] * w;
    __syncthreads();

    for (int s = tid; s < 1024; s += 256) {
        float p = 0.f;
        #pragma unroll
        for (int hh = 0; hh < 8; ++hh) p += es[hh][s];
        P[((long)b << 20) + (l << 10) + s] = f2b(p);
    }
}

// ---------------------------------------------------------------------------
// Sink: softmax over l of sink_q.k, atomicAdd (1/32)*attn into Psink[b][l].
// grid 64 = (b, h*4+si)
// ---------------------------------------------------------------------------
__global__ __launch_bounds__(256) void sink_kernel(
    const float* __restrict__ sink_q, const short* __restrict__ qkb,
    float* __restrict__ Psink)
{
    const int z = blockIdx.x;
    const int b = z >> 5;
    const int idx = z & 31;
    const int tid = threadIdx.x;

    __shared__ float sq[64];
    __shared__ float lgl[1024];
    __shared__ float red[4];
    __shared__ float mxs, invs;

    if (tid < 64) sq[tid] = sink_q[idx * 64 + tid];
    __syncthreads();

    float lmax = -1e30f;
    for (int l = tid; l < 1024; l += 256) {
        const short* kp = &qkb[(long)((b << 10) + l) * 576 + 512];
        float acc = 0.f;
        #pragma unroll
        for (int d8 = 0; d8 < 8; ++d8) {
            short8 kv = *reinterpret_cast<const short8*>(&kp[d8 * 8]);
            #pragma unroll
            for (int j = 0; j < 8; ++j) acc += b2f(kv[j]) * sq[d8 * 8 + j];
        }
        acc *= 0.125f;
        lgl[l] = acc;
        lmax = fmaxf(lmax, acc);
    }
    #pragma unroll
    for (int off = 32; off > 0; off >>= 1) lmax = fmaxf(lmax, __shfl_down(lmax, off, 64));
    if ((tid & 63) == 0) red[tid >> 6] = lmax;
    __syncthreads();
    if (tid == 0) mxs = fmaxf(fmaxf(red[0], red[1]), fmaxf(red[2], red[3]));
    __syncthreads();

    const float m = mxs;
    float psum = 0.f;
    for (int l = tid; l < 1024; l += 256) {
        float e = __expf(lgl[l] - m);
        lgl[l] = e;
        psum += e;
    }
    #pragma unroll
    for (int off = 32; off > 0; off >>= 1) psum += __shfl_down(psum, off, 64);
    if ((tid & 63) == 0) red[tid >> 6] = psum;
    __syncthreads();
    if (tid == 0) invs = 1.f / (red[0] + red[1] + red[2] + red[3]);
    __syncthreads();

    const float wgt = invs * (1.f / 32.f);
    for (int l = tid; l < 1024; l += 256)
        atomicAdd(&Psink[(b << 10) + l], lgl[l] * wgt);
}

// ---------------------------------------------------------------------------
// Ysink[b][co] = sum_l Psink[b][l] * vt[b][co][l]. grid (512, 2), wave per co.
// ---------------------------------------------------------------------------
__global__ __launch_bounds__(256) void sinky_kernel(
    const float* __restrict__ Psink, const short* __restrict__ vt,
    float* __restrict__ Ysink)
{
    const int b = blockIdx.y;
    const int tid = threadIdx.x;
    __shared__ float ps[1024];
    {
        float4 v = reinterpret_cast<const float4*>(&Psink[b << 10])[tid];
        *reinterpret_cast<float4*>(&ps[tid * 4]) = v;
    }
    __syncthreads();
    const int wave = tid >> 6;
    const int lane = tid & 63;
    const int co = blockIdx.x * 4 + wave;
    const short* vp = &vt[((long)b * 2048 + co) * 1024];
    float acc = 0.f;
    #pragma unroll
    for (int t = 0; t < 16; ++t) {
        int l = t * 64 + lane;
        acc += ps[l] * b2f(vp[l]);
    }
    #pragma unroll
    for (int off = 32; off > 0; off >>= 1) acc += __shfl_down(acc, off, 64);
    if (lane == 0) Ysink[(b << 11) + co] = acc;
}

// ---------------------------------------------------------------------------
// Fused Y-GEMM + MFMA output projection, 128x64 tile:
//  Ytile[128l x 64co] = P[b] @ vt[b]^T          (bf16 MFMA, K=1024)
//  out[128l x 64cr]   = x + bo + (Yt+Ysink) @ blockdiag(Wo)   (2nd MFMA pass)
// grid (32 co-tiles, 8 l-tiles, 2 b). Waves: wm=row half (64), wn=col half (32).
// ---------------------------------------------------------------------------
__global__ __launch_bounds__(256) void y_fused_kernel(
    const short* __restrict__ P, const short* __restrict__ vt,
    const float* __restrict__ Ysink, const float* __restrict__ Wo,
    const float* __restrict__ bo, const float* __restrict__ x,
    float* __restrict__ out)
{
    __shared__ short As[128][72];
    __shared__ short Bs[64][72];

    const int tid = threadIdx.x;
    const int b = blockIdx.z;
    const int col0 = blockIdx.x * 64;
    const int row0 = blockIdx.y * 128;
    const short* Pz = P + ((long)b << 20);
    const short* Vz = vt + ((long)b * 2048 * 1024);

    const int wave = tid >> 6;
    const int lane = tid & 63;
    const int wm = wave >> 1, wn = wave & 1;
    const int m15 = lane & 15;
    const int quad = lane >> 4;

    float4v acc[4][2];
    #pragma unroll
    for (int i = 0; i < 4; ++i)
        #pragma unroll
        for (int j = 0; j < 2; ++j)
            #pragma unroll
            for (int r = 0; r < 4; ++r) acc[i][j][r] = 0.f;

    for (int kt = 0; kt < 16; ++kt) {
        int k0 = kt * 64;
        #pragma unroll
        for (int p = 0; p < 4; ++p) {
            int i = tid + p * 256;
            int m = i >> 3, kq = i & 7;
            *reinterpret_cast<short8*>(&As[m][kq * 8]) =
                *reinterpret_cast<const short8*>(&Pz[(long)(row0 + m) * 1024 + k0 + kq * 8]);
        }
        #pragma unroll
        for (int p = 0; p < 2; ++p) {
            int i = tid + p * 256;
            int n = i >> 3, kq = i & 7;
            *reinterpret_cast<short8*>(&Bs[n][kq * 8]) =
                *reinterpret_cast<const short8*>(&Vz[(long)(col0 + n) * 1024 + k0 + kq * 8]);
        }
        __syncthreads();
        #pragma unroll
        for (int ks = 0; ks < 2; ++ks) {
            short8 a[4], bb[2];
            #pragma unroll
            for (int t = 0; t < 4; ++t)
                a[t] = *reinterpret_cast<const short8*>(&As[wm * 64 + t * 16 + m15][ks * 32 + quad * 8]);
            #pragma unroll
            for (int t = 0; t < 2; ++t)
                bb[t] = *reinterpret_cast<const short8*>(&Bs[wn * 32 + t * 16 + m15][ks * 32 + quad * 8]);
            #pragma unroll
            for (int ti = 0; ti < 4; ++ti)
                #pragma unroll
                for (int tj = 0; tj < 2; ++tj)
                    acc[ti][tj] = __builtin_amdgcn_mfma_f32_16x16x32_bf16(
                        a[ti], bb[tj], acc[ti][tj], 0, 0, 0);
        }
        __syncthreads();
    }

    // ---- epilogue pass 2: out = x + bo + (Yt + Ysink) @ blockdiag(Wo) ----
    float ysv[2];
    #pragma unroll
    for (int tj = 0; tj < 2; ++tj)
        ysv[tj] = Ysink[(b << 11) + col0 + wn * 32 + tj * 16 + m15];

    #pragma unroll
    for (int ti = 0; ti < 4; ++ti)
        #pragma unroll
        for (int r = 0; r < 4; ++r) {
            int row = wm * 64 + ti * 16 + quad * 4 + r;
            #pragma unroll
            for (int tj = 0; tj < 2; ++tj) {
                int col = wn * 32 + tj * 16 + m15;
                As[row][col] = f2b(acc[ti][tj][r] + ysv[tj]);
            }
        }
    // WoB[n][k] = (same channel) ? Wo[c0 + n/32][o=k&31][r=n&31] : 0
    const int c0 = col0 >> 5;
    for (int i = tid; i < 4096; i += 256) {
        int n = i >> 6, k = i & 63;
        short v = 0;
        if ((n >> 5) == (k >> 5))
            v = f2b(Wo[((long)(c0 + (n >> 5)) * 32 + (k & 31)) * 32 + (n & 31)]);
        Bs[n][k] = v;
    }
    __syncthreads();

    float4v acc2[4][2];
    #pragma unroll
    for (int i = 0; i < 4; ++i)
        #pragma unroll
        for (int j = 0; j < 2; ++j)
            #pragma unroll
            for (int r = 0; r < 4; ++r) acc2[i][j][r] = 0.f;

    #pragma unroll
    for (int ks = 0; ks < 2; ++ks) {
        short8 a[4], bb[2];
        #pragma unroll
        for (int t = 0; t < 4; ++t)
            a[t] = *reinterpret_cast<const short8*>(&As[wm * 64 + t * 16 + m15][ks * 32 + quad * 8]);
        #pragma unroll
        for (int t = 0; t < 2; ++t)
            bb[t] = *reinterpret_cast<const short8*>(&Bs[wn * 32 + t * 16 + m15][ks * 32 + quad * 8]);
        #pragma unroll
        for (int ti = 0; ti < 4; ++ti)
            #pragma unroll
            for (int tj = 0; tj < 2; ++tj)
                acc2[ti][tj] = __builtin_amdgcn_mfma_f32_16x16x32_bf16(
                    a[ti], bb[tj], acc2[ti][tj], 0, 0, 0);
    }

    float bov[2];
    #pragma unroll
    for (int tj = 0; tj < 2; ++tj)
        bov[tj] = bo[col0 + wn * 32 + tj * 16 + m15];

    #pragma unroll
    for (int ti = 0; ti < 4; ++ti)
        #pragma unroll
        for (int r = 0; r < 4; ++r) {
            int row = (b << 10) + row0 + wm * 64 + ti * 16 + quad * 4 + r;
            #pragma unroll
            for (int tj = 0; tj < 2; ++tj) {
                int col = col0 + wn * 32 + tj * 16 + m15;
                long oi = (long)row * 2048 + col;
                out[oi] = x[oi] + bov[tj] + acc2[ti][tj][r];
            }
        }
}

// ---------------------------------------------------------------------------
extern "C" void kernel_launch(void* const* d_in, const int* in_sizes, int n_in,
                              void* d_out, int out_size, void* d_ws, size_t ws_size,
                              hipStream_t stream)
{
    const float* x  = (const float*)d_in[0];
    const float* Wq = (const float*)d_in[1];
    const float* bq = (const float*)d_in[2];
    const float* Wk = (const float*)d_in[3];
    const float* bk = (const float*)d_in[4];
    const float* Wv = (const float*)d_in[5];
    const float* bv = (const float*)d_in[6];
    const float* Wo = (const float*)d_in[7];
    const float* bo = (const float*)d_in[8];
    const float* sq = (const float*)d_in[9];
    float* out = (float*)d_out;

    // workspace layout (float units), total ~58 MB
    float* ws = (float*)d_ws;
    float* qkpart = ws;                          // 2 x 2048x576 fp32 = 2,359,296
    short* qkb    = (short*)(ws + 2359296);      //   589,824 f (bf16)
    short* P      = (short*)(ws + 2949120);      // 1,048,576 f (2x1024x1024 bf16)
    float* Psink  = ws + 3997696;                //     2,048 f
    short* vt     = (short*)(ws + 3999744);      // 2,097,152 f (bf16)
    float* Ysink  = ws + 6096896;                //     4,096 f
    float* region = ws + 6100992;                // 8,388,608 f shared: {xb,Wt} -> S
    short* xb     = (short*)region;              // 2,097,152 f (bf16)
    short* Wt     = (short*)(region + 2097152);  //   589,824 f (bf16)
    short* Sb     = (short*)region;              // 2 x 8M bf16 = 8,388,608 f

    dim3 blk(256);

    convert_w_kernel<<<dim3(9, 32), blk, 0, stream>>>(Wq, Wk, Wt);
    vproj_kernel<<<dim3(64, 32), blk, 0, stream>>>(x, Wv, bv, vt, xb);
    qkproj_kernel<<<dim3(9, 32, 2), blk, 0, stream>>>(xb, Wt, qkpart);
    convert_qk_kernel<<<dim3(1152), blk, 0, stream>>>(qkpart, bq, bk, qkb);
    qk_s_kernel<<<dim3(16, 16, 2), blk, 0, stream>>>(qkb, Sb);
    softmax_avg_kernel<<<dim3(1024, 2), blk, 0, stream>>>(Sb, P);
    hipMemsetAsync(Psink, 0, 2048 * sizeof(float), stream);
    sink_kernel<<<dim3(64), blk, 0, stream>>>(sq, qkb, Psink);
    sinky_kernel<<<dim3(512, 2), blk, 0, stream>>>(Psink, vt, Ysink);
    y_fused_kernel<<<dim3(32, 8, 2), blk, 0, stream>>>(
        P, vt, Ysink, Wo, bo, x, out);
}